// Round 2
// baseline (8652.928 us; speedup 1.0000x reference)
//
#include <hip/hip_runtime.h>
#include <hip/hip_bf16.h>

// TextRNN: embed -> 2-layer LSTM (B=64,T=256,H=1024) -> proj to 32000, f32 out.
//  P0: convert weights f32->bf16 in MFMA-B swizzled layout [(k>>3)][n][k&7]
//  P1: embedding gather -> xs bf16 [T*B, 512]
//  P2: chunked GEMM  G = xs@Wx1cat + b1cat   (f32, 64-step chunks)
//  P3: L1 recurrence: 4 batch-groups x 64 N-blocks, Wh slice in VGPRs,
//      h[t-1] staged in XOR-swizzled LDS, c in 1 VGPR/thread.
//      Inter-block sync: DISTRIBUTED per-block flag slots (128B padded),
//      parallel 64-lane poll + one agent acquire fence. No contended RMW.
//  P4/P5: same for layer 2 (input = hs1)
//  P6: out = hT_y @ W3 + b2, split-K=2 into partials (aliased on G) + combine

typedef __attribute__((ext_vector_type(8))) short s16x8;
typedef __attribute__((ext_vector_type(4))) float f32x4;

#define N_CLASS 32000
#define EMB 512
#define HID 1024
#define BATCH 64
#define SEQ 256
#define TCHUNK 64
#define NG4 4096  // 4 gates * HID

static __device__ __forceinline__ short f2bf(float x) {
  __hip_bfloat16 h = __float2bfloat16(x);
  return *reinterpret_cast<short*>(&h);
}
static __device__ __forceinline__ float bf2f(short x) {
  __hip_bfloat16 h = *reinterpret_cast<__hip_bfloat16*>(&x);
  return __bfloat162float(h);
}
// fast activations: v_exp + v_rcp, no branches, correct at +/-inf saturation
static __device__ __forceinline__ float fsigm(float x) {
  return __builtin_amdgcn_rcpf(1.f + __expf(-x));
}
static __device__ __forceinline__ float ftanh(float x) {
  return 2.f * __builtin_amdgcn_rcpf(1.f + __expf(-2.f * x)) - 1.f;
}

// ---- P0: weight conversion to swizzled bf16 B-layout -----------------------
// dst layout: sw[((k>>3)*4096 + n)*8 + (k&7)], n = gate*1024 + j
__global__ void k_conv_w4(const float* __restrict__ Wg, const float* __restrict__ Wi,
                          const float* __restrict__ Wf, const float* __restrict__ Wo,
                          short* __restrict__ sw, int K) {
  int i = blockIdx.x * 256 + threadIdx.x;
  int k8 = i >> 10, j = i & 1023;
  if (k8 >= (K >> 3)) return;
  const float* W = blockIdx.z == 0 ? Wg : blockIdx.z == 1 ? Wi : blockIdx.z == 2 ? Wf : Wo;
  s16x8 v;
#pragma unroll
  for (int e = 0; e < 8; ++e) v[e] = f2bf(W[(size_t)(k8 * 8 + e) * 1024 + j]);
  *(s16x8*)(sw + ((size_t)k8 * NG4 + blockIdx.z * 1024 + j) * 8) = v;
}

__global__ void k_bcat(const float* __restrict__ b0, const float* __restrict__ b1,
                       const float* __restrict__ b2, const float* __restrict__ b3,
                       float* __restrict__ dst) {
  int i = blockIdx.x * 256 + threadIdx.x;  // 4096
  const float* s = (i >> 10) == 0 ? b0 : (i >> 10) == 1 ? b1 : (i >> 10) == 2 ? b2 : b3;
  dst[i] = s[i & 1023];
}

__global__ void k_f2bf(const float* __restrict__ src, short* __restrict__ dst, int n) {
  int i = blockIdx.x * 256 + threadIdx.x;
  if (i < n) dst[i] = f2bf(src[i]);
}

// ---- P1: embedding gather --------------------------------------------------
__global__ void k_embed(const int* __restrict__ X, const float* __restrict__ C,
                        short* __restrict__ xs) {
  int r = blockIdx.x;  // r = t*64 + b
  int t = r >> 6, b = r & 63;
  int idx = X[b * SEQ + t];
  const float* src = C + (size_t)idx * EMB;
  float2 v = *(const float2*)(src + threadIdx.x * 2);
  short* dst = xs + (size_t)r * EMB + threadIdx.x * 2;
  dst[0] = f2bf(v.x);
  dst[1] = f2bf(v.y);
}

// ---- P2/P4: pre-activation GEMM  C = A @ Bsw + bias ------------------------
template <int NSUB>
__global__ __launch_bounds__(256) void k_gemm(const short* __restrict__ A,
                                              const short* __restrict__ Bsw,
                                              const float* __restrict__ bias,
                                              float* __restrict__ C, int Mrows, int K,
                                              int Ntot) {
  extern __shared__ char lds_raw[];
  short* lds = (short*)lds_raw;
  constexpr int BN = 32 * NSUB;
  int tid = threadIdx.x;
  int n0 = blockIdx.x * BN;
  int nchunks = (K / 8) * BN;
  for (int cid = tid; cid < nchunks; cid += 256) {
    int k8 = cid / BN, nl = cid % BN;
    *(s16x8*)(lds + (size_t)cid * 8) = *(const s16x8*)(Bsw + ((size_t)k8 * Ntot + n0 + nl) * 8);
  }
  __syncthreads();
  int lane = tid & 63, wid = tid >> 6;
  int l15 = lane & 15, l4 = lane >> 4;
  int ms = wid >> 1, ns = wid & 1;
  for (int m0 = blockIdx.y * 64; m0 < Mrows; m0 += gridDim.y * 64) {
    f32x4 acc[2][NSUB];
#pragma unroll
    for (int i = 0; i < 2; ++i)
#pragma unroll
      for (int j = 0; j < NSUB; ++j) acc[i][j] = (f32x4){0.f, 0.f, 0.f, 0.f};
    const short* a0p = A + (size_t)(m0 + ms * 32 + l15) * K + l4 * 8;
    const short* a1p = a0p + (size_t)16 * K;
#pragma unroll 2
    for (int kc = 0; kc < K / 32; ++kc) {
      s16x8 av0 = *(const s16x8*)(a0p + kc * 32);
      s16x8 av1 = *(const s16x8*)(a1p + kc * 32);
#pragma unroll
      for (int j = 0; j < NSUB; ++j) {
        s16x8 bv = *(const s16x8*)(lds + ((size_t)(kc * 4 + l4) * BN + ns * 16 * NSUB + j * 16 + l15) * 8);
        acc[0][j] = __builtin_amdgcn_mfma_f32_16x16x32_bf16(av0, bv, acc[0][j], 0, 0, 0);
        acc[1][j] = __builtin_amdgcn_mfma_f32_16x16x32_bf16(av1, bv, acc[1][j], 0, 0, 0);
      }
    }
#pragma unroll
    for (int i = 0; i < 2; ++i)
#pragma unroll
      for (int j = 0; j < NSUB; ++j) {
        int col = n0 + ns * 16 * NSUB + j * 16 + l15;
        float bv = bias[col];
#pragma unroll
        for (int r = 0; r < 4; ++r)
          C[(size_t)(m0 + ms * 32 + i * 16 + l4 * 4 + r) * Ntot + col] = acc[i][j][r] + bv;
      }
  }
}

// ---- P3/P5: LSTM recurrence ------------------------------------------------
// 256 blocks = 4 batch-groups (16 rows) x 64 N-slices (16 h-dims).
// flags: per-layer region, [group][block] slots padded to 128B; value =
// number of global steps completed by that block (monotone; memset per launch).
__global__ __launch_bounds__(256, 1) void k_recur(
    const float* __restrict__ G, const short* __restrict__ Whsw,
    const short* __restrict__ h_init, short* __restrict__ hs, float* __restrict__ c_buf,
    const float* __restrict__ c_init, int t0, int t1, unsigned* __restrict__ flags) {
  __shared__ short a_lds[16 * HID];  // 32 KB, XOR-swizzled rows
  __shared__ float gx[4][16][16];    // gate exchange
  int tid = threadIdx.x;
  int lane = tid & 63, q = tid >> 6;
  int l15 = lane & 15, l4 = lane >> 4;
  int group = blockIdx.x >> 6, nsl = blockIdx.x & 63;
  int col = q * 1024 + nsl * 16 + l15;
  s16x8 breg[32];
#pragma unroll
  for (int kc = 0; kc < 32; ++kc)
    breg[kc] = *(const s16x8*)(Whsw + ((size_t)(kc * 4 + l4) * NG4 + col) * 8);
  int b = tid >> 4, d = tid & 15;
  float c = (t0 == 0 ? c_init : c_buf)[(group * 16 + b) * HID + nsl * 16 + d];
  unsigned* myflag = flags + ((size_t)group * 64 + nsl) * 32;
  unsigned* gflags = flags + (size_t)group * 64 * 32;
  int srow = tid >> 4, scol = tid & 15;
  // prefetch G(t0)
  f32x4 gcur, gnext;
  {
    const float* gp = G + ((size_t)group * 16 + l4 * 4) * NG4 + col;
#pragma unroll
    for (int r = 0; r < 4; ++r) gcur[r] = gp[(size_t)r * NG4];
  }
  gnext = gcur;
  for (int t = t0; t < t1; ++t) {
    if (t > t0) {
      if (tid < 64) {
        unsigned tgt = (unsigned)t;
        while (__hip_atomic_load(gflags + tid * 32, __ATOMIC_RELAXED,
                                 __HIP_MEMORY_SCOPE_AGENT) < tgt)
          __builtin_amdgcn_s_sleep(2);
      }
      __builtin_amdgcn_fence(__ATOMIC_ACQUIRE, "agent");
      __syncthreads();
    }
    const short* hsrc =
        (t == 0 ? h_init : hs + (size_t)(t - 1) * BATCH * HID) + (size_t)group * 16 * HID;
#pragma unroll
    for (int i = 0; i < 8; ++i) {
      int cidx = scol + 16 * i;
      s16x8 v = *(const s16x8*)(hsrc + srow * HID + cidx * 8);
      int byteoff = (srow * 2048 + cidx * 16) ^ ((srow & 7) << 4);
      *(s16x8*)((char*)a_lds + byteoff) = v;
    }
    __syncthreads();
    // 4 parallel MFMA chains for ILP; chain0 seeded with G(t)
    f32x4 ch0 = gcur;
    f32x4 ch1 = (f32x4){0.f, 0.f, 0.f, 0.f};
    f32x4 ch2 = (f32x4){0.f, 0.f, 0.f, 0.f};
    f32x4 ch3 = (f32x4){0.f, 0.f, 0.f, 0.f};
    // prefetch G(t+1) under the MFMAs / next barrier
    if (t + 1 < t1) {
      const float* gp = G + ((size_t)(t + 1 - t0) * BATCH + group * 16 + l4 * 4) * NG4 + col;
#pragma unroll
      for (int r = 0; r < 4; ++r) gnext[r] = gp[(size_t)r * NG4];
    }
#pragma unroll
    for (int kc = 0; kc < 32; kc += 4) {
      int bo0 = (l15 * 2048 + (kc + 0) * 64 + l4 * 16) ^ ((l15 & 7) << 4);
      int bo1 = (l15 * 2048 + (kc + 1) * 64 + l4 * 16) ^ ((l15 & 7) << 4);
      int bo2 = (l15 * 2048 + (kc + 2) * 64 + l4 * 16) ^ ((l15 & 7) << 4);
      int bo3 = (l15 * 2048 + (kc + 3) * 64 + l4 * 16) ^ ((l15 & 7) << 4);
      s16x8 a0 = *(const s16x8*)((const char*)a_lds + bo0);
      s16x8 a1 = *(const s16x8*)((const char*)a_lds + bo1);
      s16x8 a2 = *(const s16x8*)((const char*)a_lds + bo2);
      s16x8 a3 = *(const s16x8*)((const char*)a_lds + bo3);
      ch0 = __builtin_amdgcn_mfma_f32_16x16x32_bf16(a0, breg[kc + 0], ch0, 0, 0, 0);
      ch1 = __builtin_amdgcn_mfma_f32_16x16x32_bf16(a1, breg[kc + 1], ch1, 0, 0, 0);
      ch2 = __builtin_amdgcn_mfma_f32_16x16x32_bf16(a2, breg[kc + 2], ch2, 0, 0, 0);
      ch3 = __builtin_amdgcn_mfma_f32_16x16x32_bf16(a3, breg[kc + 3], ch3, 0, 0, 0);
    }
    f32x4 acc = (ch0 + ch1) + (ch2 + ch3);
#pragma unroll
    for (int r = 0; r < 4; ++r) gx[q][l4 * 4 + r][l15] = acc[r];
    __syncthreads();
    float gg = ftanh(gx[0][b][d]);
    float gi = fsigm(gx[1][b][d]);
    float gf = fsigm(gx[2][b][d]);
    float go = fsigm(gx[3][b][d]);
    c = c * gf + gg * gi;
    float h = ftanh(c) * go;
    hs[(size_t)t * BATCH * HID + (group * 16 + b) * HID + nsl * 16 + d] = f2bf(h);
    __syncthreads();  // per-wave vmcnt(0) drain before barrier -> stores in L2
    if (tid == 0)
      __hip_atomic_store(myflag, (unsigned)(t + 1), __ATOMIC_RELEASE,
                         __HIP_MEMORY_SCOPE_AGENT);
    gcur = gnext;
  }
  c_buf[(group * 16 + b) * HID + nsl * 16 + d] = c;
}

// ---- P6: out = hT @ W3 + b2, split-K=2 -------------------------------------
__global__ __launch_bounds__(256) void k_final(const short* __restrict__ hT,
                                               const float* __restrict__ W3,
                                               float* __restrict__ partial) {
  __shared__ float hst[64][64];  // [k][b]
  int tid = threadIdx.x;
  int n = blockIdx.x * 256 + tid;
  int kbase = blockIdx.y * 512;
  float acc[64];
#pragma unroll
  for (int i = 0; i < 64; ++i) acc[i] = 0.f;
  int bb = tid >> 2, part = tid & 3;
  for (int kc = kbase; kc < kbase + 512; kc += 64) {
    __syncthreads();
    s16x8 v0 = *(const s16x8*)(hT + bb * HID + kc + part * 16);
    s16x8 v1 = *(const s16x8*)(hT + bb * HID + kc + part * 16 + 8);
#pragma unroll
    for (int e = 0; e < 8; ++e) {
      hst[part * 16 + e][bb] = bf2f(v0[e]);
      hst[part * 16 + 8 + e][bb] = bf2f(v1[e]);
    }
    __syncthreads();
    for (int k = 0; k < 64; ++k) {
      float wv = W3[(size_t)(kbase + (kc - kbase) + k) * N_CLASS + n];
      const float4* hp = (const float4*)&hst[(kc - kbase) & 63 ? 0 : 0][0];  // placeholder
      (void)hp;
      const float4* hp2 = (const float4*)&hst[k][0];
#pragma unroll
      for (int b4 = 0; b4 < 16; ++b4) {
        float4 h4 = hp2[b4];
        acc[b4 * 4 + 0] += h4.x * wv;
        acc[b4 * 4 + 1] += h4.y * wv;
        acc[b4 * 4 + 2] += h4.z * wv;
        acc[b4 * 4 + 3] += h4.w * wv;
      }
    }
  }
#pragma unroll
  for (int b = 0; b < 64; ++b)
    partial[((size_t)blockIdx.y * 64 + b) * N_CLASS + n] = acc[b];
}

__global__ void k_fincomb(const float* __restrict__ partial, const float* __restrict__ b2,
                          float* __restrict__ out) {
  int n = blockIdx.x * 256 + threadIdx.x;  // gridDim.x = 125
  int b = blockIdx.y;                      // gridDim.y = 64
  out[(size_t)b * N_CLASS + n] =
      partial[(size_t)b * N_CLASS + n] + partial[((size_t)64 + b) * N_CLASS + n] + b2[n];
}

extern "C" void kernel_launch(void* const* d_in, const int* in_sizes, int n_in, void* d_out,
                              int out_size, void* d_ws, size_t ws_size, hipStream_t stream) {
  (void)in_sizes; (void)n_in; (void)out_size; (void)ws_size;
  const int* X = (const int*)d_in[0];
  const float* C = (const float*)d_in[1];
  const float* W1 = (const float*)d_in[2];
  const float* W_xi = (const float*)d_in[3];
  const float* W_xf = (const float*)d_in[4];
  const float* W_xo = (const float*)d_in[5];
  const float* W2 = (const float*)d_in[6];
  const float* W_hi = (const float*)d_in[7];
  const float* W_hf = (const float*)d_in[8];
  const float* W_ho = (const float*)d_in[9];
  const float* b1 = (const float*)d_in[10];
  const float* b_i = (const float*)d_in[11];
  const float* b_f = (const float*)d_in[12];
  const float* b_o = (const float*)d_in[13];
  const float* W1_y = (const float*)d_in[14];
  const float* W_xi_y = (const float*)d_in[15];
  const float* W_xf_y = (const float*)d_in[16];
  const float* W_xo_y = (const float*)d_in[17];
  const float* W2_y = (const float*)d_in[18];
  const float* W_hi_y = (const float*)d_in[19];
  const float* W_hf_y = (const float*)d_in[20];
  const float* W_ho_y = (const float*)d_in[21];
  const float* b1_y = (const float*)d_in[22];
  const float* b_i_y = (const float*)d_in[23];
  const float* b_f_y = (const float*)d_in[24];
  const float* b_o_y = (const float*)d_in[25];
  const float* W3 = (const float*)d_in[26];
  const float* b2 = (const float*)d_in[27];
  const float* h0 = (const float*)d_in[28];
  const float* c0 = (const float*)d_in[29];
  const float* h0_y = (const float*)d_in[30];
  const float* c0_y = (const float*)d_in[31];

  char* w = (char*)d_ws;
  size_t off = 0;
  auto take = [&](size_t bytes) {
    char* p = w + off;
    off += (bytes + 255) & ~(size_t)255;
    return p;
  };
  short* wx1 = (short*)take(512UL * NG4 * 2);
  short* wh1 = (short*)take(1024UL * NG4 * 2);
  short* wx2 = (short*)take(1024UL * NG4 * 2);
  short* wh2 = (short*)take(1024UL * NG4 * 2);
  short* xs = (short*)take((size_t)SEQ * BATCH * EMB * 2);
  short* hs1 = (short*)take((size_t)SEQ * BATCH * HID * 2);
  short* hs2 = (short*)take((size_t)SEQ * BATCH * HID * 2);
  float* G = (float*)take((size_t)TCHUNK * BATCH * NG4 * 4);  // also partials for k_final
  float* bc1 = (float*)take(NG4 * 4);
  float* bc2 = (float*)take(NG4 * 4);
  short* h0b = (short*)take((size_t)BATCH * HID * 2);
  short* h0yb = (short*)take((size_t)BATCH * HID * 2);
  float* cb1 = (float*)take((size_t)BATCH * HID * 4);
  float* cb2 = (float*)take((size_t)BATCH * HID * 4);
  unsigned* flags = (unsigned*)take(65536);  // 2 layers x 4 groups x 64 slots x 128B

  hipMemsetAsync(flags, 0, 65536, stream);
  k_bcat<<<16, 256, 0, stream>>>(b1, b_i, b_f, b_o, bc1);
  k_bcat<<<16, 256, 0, stream>>>(b1_y, b_i_y, b_f_y, b_o_y, bc2);
  k_f2bf<<<256, 256, 0, stream>>>(h0, h0b, BATCH * HID);
  k_f2bf<<<256, 256, 0, stream>>>(h0_y, h0yb, BATCH * HID);
  k_conv_w4<<<dim3(256, 1, 4), 256, 0, stream>>>(W1, W_xi, W_xf, W_xo, wx1, 512);
  k_conv_w4<<<dim3(512, 1, 4), 256, 0, stream>>>(W2, W_hi, W_hf, W_ho, wh1, 1024);
  k_conv_w4<<<dim3(512, 1, 4), 256, 0, stream>>>(W1_y, W_xi_y, W_xf_y, W_xo_y, wx2, 1024);
  k_conv_w4<<<dim3(512, 1, 4), 256, 0, stream>>>(W2_y, W_hi_y, W_hf_y, W_ho_y, wh2, 1024);
  k_embed<<<SEQ * BATCH, 256, 0, stream>>>(X, C, xs);

  for (int seg = 0; seg < 4; ++seg) {
    int t0 = seg * TCHUNK;
    k_gemm<2><<<dim3(64, 8), 256, 512 * 64 * 2, stream>>>(
        xs + (size_t)t0 * BATCH * EMB, wx1, bc1, G, TCHUNK * BATCH, 512, NG4);
    k_recur<<<256, 256, 0, stream>>>(G, wh1, h0b, hs1, cb1, c0, t0, t0 + TCHUNK, flags);
  }
  for (int seg = 0; seg < 4; ++seg) {
    int t0 = seg * TCHUNK;
    k_gemm<1><<<dim3(128, 4), 256, 1024 * 32 * 2, stream>>>(
        hs1 + (size_t)t0 * BATCH * HID, wx2, bc2, G, TCHUNK * BATCH, 1024, NG4);
    k_recur<<<256, 256, 0, stream>>>(G, wh2, h0yb, hs2, cb2, c0_y, t0, t0 + TCHUNK,
                                     flags + 8192);
  }
  k_final<<<dim3(125, 2), 256, 0, stream>>>(hs2 + (size_t)(SEQ - 1) * BATCH * HID, W3, G);
  k_fincomb<<<dim3(125, 64), 256, 0, stream>>>(G, b2, (float*)d_out);
}

// Round 3
// 5793.517 us; speedup vs baseline: 1.4936x; 1.4936x over previous
//
#include <hip/hip_runtime.h>
#include <hip/hip_bf16.h>

// TextRNN: embed -> 2-layer LSTM (B=64,T=256,H=1024) -> proj 32000, f32 out.
// R3 design:
//  - G1 = xs@Wx1+b1 precomputed for ALL t, bf16, MFMA-packed layout (k_gemx)
//  - ONE persistent kernel (k_mega) runs 257 rounds: round r computes
//    h1(r) (r<256) and h2(r-1) (r>=1). 256 blocks = 4 groups x 64 n-slices.
//    Wh1/Wx2/Wh2 slices in registers (384 VGPR). h exchanged via 512KB ring
//    with L2-BYPASSING agent-scope 8B atomics (no wbl2/inv per round).
//  - Barrier: arrival slots + 1 aggregator/group + 1 published line.
//  - Gate exchange in-wave via shuffles (col remap), no LDS gx.
//  - final: hT_y @ W3 + b2 split-K=2 (partials alias G1 buffer).

typedef __attribute__((ext_vector_type(8))) short s16x8;
typedef __attribute__((ext_vector_type(4))) float f32x4;
typedef unsigned long long u64;

#define N_CLASS 32000
#define EMB 512
#define HID 1024
#define BATCH 64
#define SEQ 256
#define NG4 4096

static __device__ __forceinline__ short f2bf(float x) {
  __hip_bfloat16 h = __float2bfloat16(x);
  return *reinterpret_cast<short*>(&h);
}
static __device__ __forceinline__ float bf2f(short x) {
  __hip_bfloat16 h = *reinterpret_cast<__hip_bfloat16*>(&x);
  return __bfloat162float(h);
}
static __device__ __forceinline__ float fsigm(float x) {
  return __builtin_amdgcn_rcpf(1.f + __expf(-x));
}
static __device__ __forceinline__ float ftanh(float x) {
  return 2.f * __builtin_amdgcn_rcpf(1.f + __expf(-2.f * x)) - 1.f;
}

// ---- weight conversion to swizzled bf16 B-layout: sw[((k>>3)*4096+n)*8+(k&7)]
__global__ void k_conv_w4(const float* __restrict__ Wg, const float* __restrict__ Wi,
                          const float* __restrict__ Wf, const float* __restrict__ Wo,
                          short* __restrict__ sw, int K) {
  int i = blockIdx.x * 256 + threadIdx.x;
  int k8 = i >> 10, j = i & 1023;
  if (k8 >= (K >> 3)) return;
  const float* W = blockIdx.z == 0 ? Wg : blockIdx.z == 1 ? Wi : blockIdx.z == 2 ? Wf : Wo;
  s16x8 v;
#pragma unroll
  for (int e = 0; e < 8; ++e) v[e] = f2bf(W[(size_t)(k8 * 8 + e) * 1024 + j]);
  *(s16x8*)(sw + ((size_t)k8 * NG4 + blockIdx.z * 1024 + j) * 8) = v;
}

__global__ void k_bcat(const float* __restrict__ b0, const float* __restrict__ b1,
                       const float* __restrict__ b2, const float* __restrict__ b3,
                       float* __restrict__ dst) {
  int i = blockIdx.x * 256 + threadIdx.x;  // 4096
  const float* s = (i >> 10) == 0 ? b0 : (i >> 10) == 1 ? b1 : (i >> 10) == 2 ? b2 : b3;
  dst[i] = s[i & 1023];
}

__global__ void k_f2bf(const float* __restrict__ src, short* __restrict__ dst, int n) {
  int i = blockIdx.x * 256 + threadIdx.x;
  if (i < n) dst[i] = f2bf(src[i]);
}

// ---- embedding gather: xs[t*64+b][:] = bf16(C[X[b][t]]) ----------------------
__global__ void k_embed(const int* __restrict__ X, const float* __restrict__ C,
                        short* __restrict__ xs) {
  int r = blockIdx.x;
  int t = r >> 6, b = r & 63;
  int idx = X[b * SEQ + t];
  const float* src = C + (size_t)idx * EMB;
  float2 v = *(const float2*)(src + threadIdx.x * 2);
  short* dst = xs + (size_t)r * EMB + threadIdx.x * 2;
  dst[0] = f2bf(v.x);
  dst[1] = f2bf(v.y);
}

// ---- G1 pre-GEMM: Gsw (bf16 packed u64 per (t,g,nsl,q,lane)) = xs@Wx1 + b1 ---
__global__ __launch_bounds__(256) void k_gemx(const short* __restrict__ A,
                                              const short* __restrict__ Bsw,
                                              const float* __restrict__ bias,
                                              u64* __restrict__ Gsw) {
  __shared__ short lds[4096 * 8];  // 64KB B panel (K=512 x BN=64)
  int tid = threadIdx.x;
  int n0 = blockIdx.x * 64;
  for (int cid = tid; cid < 4096; cid += 256) {
    int k8 = cid >> 6, nl = cid & 63;
    *(s16x8*)(lds + (size_t)cid * 8) = *(const s16x8*)(Bsw + ((size_t)k8 * NG4 + n0 + nl) * 8);
  }
  __syncthreads();
  int lane = tid & 63, wid = tid >> 6;
  int l15 = lane & 15, l4 = lane >> 4;
  int ms = wid >> 1, ns = wid & 1;
  for (int m0 = blockIdx.y * 64; m0 < SEQ * BATCH; m0 += gridDim.y * 64) {
    f32x4 acc[2][2];
#pragma unroll
    for (int i = 0; i < 2; ++i)
#pragma unroll
      for (int j = 0; j < 2; ++j) acc[i][j] = (f32x4){0.f, 0.f, 0.f, 0.f};
    const short* a0p = A + (size_t)(m0 + ms * 32 + l15) * EMB + l4 * 8;
    const short* a1p = a0p + (size_t)16 * EMB;
#pragma unroll 4
    for (int kc = 0; kc < 16; ++kc) {
      s16x8 av0 = *(const s16x8*)(a0p + kc * 32);
      s16x8 av1 = *(const s16x8*)(a1p + kc * 32);
#pragma unroll
      for (int j = 0; j < 2; ++j) {
        s16x8 bv = *(const s16x8*)(lds + (size_t)((kc * 4 + l4) * 64 + ns * 32 + j * 16 + l15) * 8);
        acc[0][j] = __builtin_amdgcn_mfma_f32_16x16x32_bf16(av0, bv, acc[0][j], 0, 0, 0);
        acc[1][j] = __builtin_amdgcn_mfma_f32_16x16x32_bf16(av1, bv, acc[1][j], 0, 0, 0);
      }
    }
    int t = m0 >> 6;
#pragma unroll
    for (int i = 0; i < 2; ++i)
#pragma unroll
      for (int j = 0; j < 2; ++j) {
        int grp = ms * 2 + i;
        int colg = n0 + ns * 32 + j * 16 + l15;
        float bv = bias[colg];
        int q = colg >> 10, nslc = (colg >> 4) & 63;
        u64 pk = 0;
#pragma unroll
        for (int e = 0; e < 4; ++e)
          pk |= (u64)(unsigned short)f2bf(acc[i][j][e] + bv) << (16 * e);
        size_t slot = ((((size_t)t * 4 + grp) * 64 + nslc) * 4 + q) * 64 + l4 * 16 + l15;
        Gsw[slot] = pk;
      }
  }
}

// ---- persistent 2-layer recurrence ------------------------------------------
// 256 blocks = 4 groups (16 batch rows) x 64 n-slices (16 h dims).
// Wave wv covers all 4 gates x dims [nsl*16 + wv*4 .. +4).
// col(lane) = (l15>>2)*1024 + nsl*16 + wv*4 + (l15&3).
__global__ __launch_bounds__(256, 1) void k_mega(
    const u64* __restrict__ G64, const short* __restrict__ Wh1sw,
    const short* __restrict__ Wx2sw, const short* __restrict__ Wh2sw,
    const float* __restrict__ bc2, u64* __restrict__ h1ex, u64* __restrict__ h2ex,
    const float* __restrict__ c0, const float* __restrict__ c0y,
    u64* __restrict__ hTy, unsigned* __restrict__ flags) {
  __shared__ short a_lds[2 * 16 * 1024];  // 64KB: A1 | A2, XOR-swizzled rows
  const int tid = threadIdx.x;
  const int lane = tid & 63, wv = tid >> 6;
  const int l15 = lane & 15, l4 = lane >> 4;
  const int group = (int)blockIdx.x >> 6, nsl = (int)blockIdx.x & 63;
  const int col = (l15 >> 2) * 1024 + nsl * 16 + wv * 4 + (l15 & 3);

  s16x8 b1r[32], bxr[32], b2r[32];
#pragma unroll 8
  for (int kc = 0; kc < 32; ++kc) {
    size_t o = ((size_t)(kc * 4 + l4) * NG4 + col) * 8;
    b1r[kc] = *(const s16x8*)(Wh1sw + o);
    bxr[kc] = *(const s16x8*)(Wx2sw + o);
    b2r[kc] = *(const s16x8*)(Wh2sw + o);
  }
  const float bias2 = bc2[col];
  float c1v[4], c2v[4];
#pragma unroll
  for (int e = 0; e < 4; ++e) {
    int gi = (group * 16 + l4 * 4 + e) * HID + nsl * 16 + wv * 4 + (l15 & 3);
    c1v[e] = c0[gi];
    c2v[e] = c0y[gi];
  }
  unsigned* arr = flags;           // [4][64] slots, stride 32 u32 (128B)
  unsigned* done = flags + 8192;   // [4] lines, stride 32 u32
  const int srow = tid >> 4, scol = tid & 15;
  const int exrow = (group * 16 + srow) * 256;
  const size_t gbase =
      (((size_t)group * 64 + nsl) * 4 + (l15 >> 2)) * 64 + l4 * 16 + wv * 4 + (l15 & 3);
  u64 gcur = G64[gbase], gnext = 0;
  const int gsrc = l4 * 16 + (l15 & 3);
  const int psrc = ((l15 >> 2) << 4) + ((l15 & 3) << 2);
  const int swzm = (l15 & 7) << 4;
  const int abase = l15 * 2048 + l4 * 16;

  for (int r = 0; r <= 256; ++r) {
    if (r > 0) {
      if (nsl == 0) {
        if (tid < 64) {
          unsigned* p = arr + ((group << 6) + tid) * 32;
          while (__hip_atomic_load(p, __ATOMIC_RELAXED, __HIP_MEMORY_SCOPE_AGENT) <
                 (unsigned)r)
            __builtin_amdgcn_s_sleep(2);
        }
        if (tid == 0)
          __hip_atomic_store(done + group * 32, (unsigned)r, __ATOMIC_RELAXED,
                             __HIP_MEMORY_SCOPE_AGENT);
      } else if (tid == 0) {
        while (__hip_atomic_load(done + group * 32, __ATOMIC_RELAXED,
                                 __HIP_MEMORY_SCOPE_AGENT) < (unsigned)r)
          __builtin_amdgcn_s_sleep(2);
      }
      __syncthreads();
      asm volatile("" ::: "memory");
    }
    {  // stage A1 = h1(r-1), A2 = h2(r-2) from ring slot (r+1)&1
      const int slot = (r + 1) & 1;
      const u64* s1 = h1ex + slot * 16384 + exrow;
      const u64* s2 = h2ex + slot * 16384 + exrow;
#pragma unroll 4
      for (int i = 0; i < 16; ++i) {
        int chunk = scol + (i << 4);
        u64 v1 = __hip_atomic_load(s1 + chunk, __ATOMIC_RELAXED, __HIP_MEMORY_SCOPE_AGENT);
        u64 v2 = __hip_atomic_load(s2 + chunk, __ATOMIC_RELAXED, __HIP_MEMORY_SCOPE_AGENT);
        int bo = (srow * 2048 + chunk * 8) ^ ((srow & 7) << 4);
        *(u64*)((char*)a_lds + bo) = v1;
        *(u64*)((char*)a_lds + 32768 + bo) = v2;
      }
    }
    __syncthreads();
    if (r + 1 < 256) gnext = G64[gbase + (size_t)(r + 1) * 65536];

    if (r < 256) {  // ---- layer 1: gates = G1(r) + h1(r-1)@Wh1 ----
      f32x4 ch0, ch1, ch2, ch3;
#pragma unroll
      for (int e = 0; e < 4; ++e)
        ch0[e] = __uint_as_float((unsigned)((gcur >> (16 * e)) & 0xffffu) << 16);
      ch1 = ch2 = ch3 = (f32x4){0.f, 0.f, 0.f, 0.f};
#pragma unroll
      for (int kc = 0; kc < 32; kc += 4) {
        s16x8 a0 = *(const s16x8*)((const char*)a_lds + ((abase + (kc + 0) * 64) ^ swzm));
        s16x8 a1 = *(const s16x8*)((const char*)a_lds + ((abase + (kc + 1) * 64) ^ swzm));
        s16x8 a2 = *(const s16x8*)((const char*)a_lds + ((abase + (kc + 2) * 64) ^ swzm));
        s16x8 a3 = *(const s16x8*)((const char*)a_lds + ((abase + (kc + 3) * 64) ^ swzm));
        ch0 = __builtin_amdgcn_mfma_f32_16x16x32_bf16(a0, b1r[kc + 0], ch0, 0, 0, 0);
        ch1 = __builtin_amdgcn_mfma_f32_16x16x32_bf16(a1, b1r[kc + 1], ch1, 0, 0, 0);
        ch2 = __builtin_amdgcn_mfma_f32_16x16x32_bf16(a2, b1r[kc + 2], ch2, 0, 0, 0);
        ch3 = __builtin_amdgcn_mfma_f32_16x16x32_bf16(a3, b1r[kc + 3], ch3, 0, 0, 0);
      }
      f32x4 acc = (ch0 + ch1) + (ch2 + ch3);
      float hh0, hh1, hh2, hh3;
#pragma unroll
      for (int e = 0; e < 4; ++e) {
        float xg = __shfl(acc[e], gsrc + 0);
        float xi = __shfl(acc[e], gsrc + 4);
        float xf = __shfl(acc[e], gsrc + 8);
        float xo = __shfl(acc[e], gsrc + 12);
        float cn = c1v[e] * fsigm(xf) + ftanh(xg) * fsigm(xi);
        c1v[e] = cn;
        float hv = ftanh(cn) * fsigm(xo);
        if (e == 0) hh0 = hv;
        else if (e == 1) hh1 = hv;
        else if (e == 2) hh2 = hv;
        else hh3 = hv;
      }
      int rr = l15 >> 2;
      float hexp = rr == 0 ? hh0 : rr == 1 ? hh1 : rr == 2 ? hh2 : hh3;
      float p0 = __shfl(hexp, psrc + 0);
      float p1 = __shfl(hexp, psrc + 1);
      float p2 = __shfl(hexp, psrc + 2);
      float p3 = __shfl(hexp, psrc + 3);
      if (lane < 16) {
        u64 pk = (u64)(unsigned short)f2bf(p0) | ((u64)(unsigned short)f2bf(p1) << 16) |
                 ((u64)(unsigned short)f2bf(p2) << 32) |
                 ((u64)(unsigned short)f2bf(p3) << 48);
        __hip_atomic_store(h1ex + (r & 1) * 16384 + (group * 16 + lane) * 256 + nsl * 4 + wv,
                           pk, __ATOMIC_RELAXED, __HIP_MEMORY_SCOPE_AGENT);
      }
    }

    if (r >= 1) {  // ---- layer 2: gates = b2 + h1(r-1)@Wx2 + h2(r-2)@Wh2 ----
      f32x4 ch0 = (f32x4){bias2, bias2, bias2, bias2};
      f32x4 ch1 = (f32x4){0.f, 0.f, 0.f, 0.f};
      f32x4 ch2 = (f32x4){0.f, 0.f, 0.f, 0.f};
      f32x4 ch3 = (f32x4){0.f, 0.f, 0.f, 0.f};
#pragma unroll
      for (int kc = 0; kc < 32; kc += 2) {
        int o0 = (abase + (kc + 0) * 64) ^ swzm;
        int o1 = (abase + (kc + 1) * 64) ^ swzm;
        s16x8 a10 = *(const s16x8*)((const char*)a_lds + o0);
        s16x8 a20 = *(const s16x8*)((const char*)a_lds + 32768 + o0);
        s16x8 a11 = *(const s16x8*)((const char*)a_lds + o1);
        s16x8 a21 = *(const s16x8*)((const char*)a_lds + 32768 + o1);
        ch0 = __builtin_amdgcn_mfma_f32_16x16x32_bf16(a10, bxr[kc + 0], ch0, 0, 0, 0);
        ch1 = __builtin_amdgcn_mfma_f32_16x16x32_bf16(a20, b2r[kc + 0], ch1, 0, 0, 0);
        ch2 = __builtin_amdgcn_mfma_f32_16x16x32_bf16(a11, bxr[kc + 1], ch2, 0, 0, 0);
        ch3 = __builtin_amdgcn_mfma_f32_16x16x32_bf16(a21, b2r[kc + 1], ch3, 0, 0, 0);
      }
      f32x4 acc = (ch0 + ch1) + (ch2 + ch3);
      float hh0, hh1, hh2, hh3;
#pragma unroll
      for (int e = 0; e < 4; ++e) {
        float xg = __shfl(acc[e], gsrc + 0);
        float xi = __shfl(acc[e], gsrc + 4);
        float xf = __shfl(acc[e], gsrc + 8);
        float xo = __shfl(acc[e], gsrc + 12);
        float cn = c2v[e] * fsigm(xf) + ftanh(xg) * fsigm(xi);
        c2v[e] = cn;
        float hv = ftanh(cn) * fsigm(xo);
        if (e == 0) hh0 = hv;
        else if (e == 1) hh1 = hv;
        else if (e == 2) hh2 = hv;
        else hh3 = hv;
      }
      int rr = l15 >> 2;
      float hexp = rr == 0 ? hh0 : rr == 1 ? hh1 : rr == 2 ? hh2 : hh3;
      float p0 = __shfl(hexp, psrc + 0);
      float p1 = __shfl(hexp, psrc + 1);
      float p2 = __shfl(hexp, psrc + 2);
      float p3 = __shfl(hexp, psrc + 3);
      if (lane < 16) {
        u64 pk = (u64)(unsigned short)f2bf(p0) | ((u64)(unsigned short)f2bf(p1) << 16) |
                 ((u64)(unsigned short)f2bf(p2) << 32) |
                 ((u64)(unsigned short)f2bf(p3) << 48);
        int idx = (group * 16 + lane) * 256 + nsl * 4 + wv;
        if (r < 256)
          __hip_atomic_store(h2ex + (r & 1) * 16384 + idx, pk, __ATOMIC_RELAXED,
                             __HIP_MEMORY_SCOPE_AGENT);
        else
          hTy[idx] = pk;  // h2(255) = hT_y, plain store (flushed at kernel end)
      }
    }

    if (r < 256) {
      asm volatile("s_waitcnt vmcnt(0)" ::: "memory");
      __syncthreads();  // all waves' h stores acked before arrival
      if (tid == 0)
        __hip_atomic_store(arr + ((group << 6) + nsl) * 32, (unsigned)(r + 1),
                           __ATOMIC_RELAXED, __HIP_MEMORY_SCOPE_AGENT);
    }
    gcur = gnext;
  }
}

// ---- final projection, split-K=2 --------------------------------------------
__global__ __launch_bounds__(256) void k_final(const short* __restrict__ hT,
                                               const float* __restrict__ W3,
                                               float* __restrict__ partial) {
  __shared__ float hst[64][64];
  int tid = threadIdx.x;
  int n = blockIdx.x * 256 + tid;
  int kbase = blockIdx.y * 512;
  float acc[64];
#pragma unroll
  for (int i = 0; i < 64; ++i) acc[i] = 0.f;
  int bb = tid >> 2, part = tid & 3;
  for (int kc = 0; kc < 512; kc += 64) {
    __syncthreads();
    s16x8 v0 = *(const s16x8*)(hT + bb * HID + kbase + kc + part * 16);
    s16x8 v1 = *(const s16x8*)(hT + bb * HID + kbase + kc + part * 16 + 8);
#pragma unroll
    for (int e = 0; e < 8; ++e) {
      hst[part * 16 + e][bb] = bf2f(v0[e]);
      hst[part * 16 + 8 + e][bb] = bf2f(v1[e]);
    }
    __syncthreads();
    for (int k = 0; k < 64; ++k) {
      float wv = W3[(size_t)(kbase + kc + k) * N_CLASS + n];
      const float4* hp = (const float4*)&hst[k][0];
#pragma unroll
      for (int b4 = 0; b4 < 16; ++b4) {
        float4 h4 = hp[b4];
        acc[b4 * 4 + 0] += h4.x * wv;
        acc[b4 * 4 + 1] += h4.y * wv;
        acc[b4 * 4 + 2] += h4.z * wv;
        acc[b4 * 4 + 3] += h4.w * wv;
      }
    }
  }
#pragma unroll
  for (int b = 0; b < 64; ++b)
    partial[((size_t)blockIdx.y * 64 + b) * N_CLASS + n] = acc[b];
}

__global__ void k_fincomb(const float* __restrict__ partial, const float* __restrict__ b2,
                          float* __restrict__ out) {
  int n = blockIdx.x * 256 + threadIdx.x;
  int b = blockIdx.y;
  out[(size_t)b * N_CLASS + n] =
      partial[(size_t)b * N_CLASS + n] + partial[((size_t)64 + b) * N_CLASS + n] + b2[n];
}

extern "C" void kernel_launch(void* const* d_in, const int* in_sizes, int n_in, void* d_out,
                              int out_size, void* d_ws, size_t ws_size, hipStream_t stream) {
  (void)in_sizes; (void)n_in; (void)out_size; (void)ws_size;
  const int* X = (const int*)d_in[0];
  const float* C = (const float*)d_in[1];
  const float* W1 = (const float*)d_in[2];
  const float* W_xi = (const float*)d_in[3];
  const float* W_xf = (const float*)d_in[4];
  const float* W_xo = (const float*)d_in[5];
  const float* W2 = (const float*)d_in[6];
  const float* W_hi = (const float*)d_in[7];
  const float* W_hf = (const float*)d_in[8];
  const float* W_ho = (const float*)d_in[9];
  const float* b1 = (const float*)d_in[10];
  const float* b_i = (const float*)d_in[11];
  const float* b_f = (const float*)d_in[12];
  const float* b_o = (const float*)d_in[13];
  const float* W1_y = (const float*)d_in[14];
  const float* W_xi_y = (const float*)d_in[15];
  const float* W_xf_y = (const float*)d_in[16];
  const float* W_xo_y = (const float*)d_in[17];
  const float* W2_y = (const float*)d_in[18];
  const float* W_hi_y = (const float*)d_in[19];
  const float* W_hf_y = (const float*)d_in[20];
  const float* W_ho_y = (const float*)d_in[21];
  const float* b1_y = (const float*)d_in[22];
  const float* b_i_y = (const float*)d_in[23];
  const float* b_f_y = (const float*)d_in[24];
  const float* b_o_y = (const float*)d_in[25];
  const float* W3 = (const float*)d_in[26];
  const float* b2 = (const float*)d_in[27];
  const float* h0 = (const float*)d_in[28];
  const float* c0 = (const float*)d_in[29];
  const float* h0_y = (const float*)d_in[30];
  const float* c0_y = (const float*)d_in[31];

  char* w = (char*)d_ws;
  size_t off = 0;
  auto take = [&](size_t bytes) {
    char* p = w + off;
    off += (bytes + 255) & ~(size_t)255;
    return p;
  };
  short* wx1 = (short*)take(64UL * NG4 * 8 * 2);    // 4MB
  short* wh1 = (short*)take(128UL * NG4 * 8 * 2);   // 8MB
  short* wx2 = (short*)take(128UL * NG4 * 8 * 2);   // 8MB
  short* wh2 = (short*)take(128UL * NG4 * 8 * 2);   // 8MB
  short* xs = (short*)take((size_t)SEQ * BATCH * EMB * 2);   // 16MB
  u64* G1sw = (u64*)take((size_t)SEQ * 65536 * 8);  // 134MB; partials alias later
  float* bc1 = (float*)take(NG4 * 4);
  float* bc2 = (float*)take(NG4 * 4);
  u64* h1ex = (u64*)take(2UL * 16384 * 8);  // 256KB ring
  u64* h2ex = (u64*)take(2UL * 16384 * 8);
  u64* hTy = (u64*)take(16384UL * 8);       // 128KB
  unsigned* flags = (unsigned*)take(65536);

  hipMemsetAsync(flags, 0, 65536, stream);
  k_bcat<<<16, 256, 0, stream>>>(b1, b_i, b_f, b_o, bc1);
  k_bcat<<<16, 256, 0, stream>>>(b1_y, b_i_y, b_f_y, b_o_y, bc2);
  // seed rings: h1ex slot1 <- h0 (read at r=0), h2ex slot0 <- h0_y (read at r=1)
  k_f2bf<<<256, 256, 0, stream>>>(h0, (short*)h1ex + 65536, BATCH * HID);
  k_f2bf<<<256, 256, 0, stream>>>(h0_y, (short*)h2ex, BATCH * HID);
  k_conv_w4<<<dim3(256, 1, 4), 256, 0, stream>>>(W1, W_xi, W_xf, W_xo, wx1, 512);
  k_conv_w4<<<dim3(512, 1, 4), 256, 0, stream>>>(W2, W_hi, W_hf, W_ho, wh1, 1024);
  k_conv_w4<<<dim3(512, 1, 4), 256, 0, stream>>>(W1_y, W_xi_y, W_xf_y, W_xo_y, wx2, 1024);
  k_conv_w4<<<dim3(512, 1, 4), 256, 0, stream>>>(W2_y, W_hi_y, W_hf_y, W_ho_y, wh2, 1024);
  k_embed<<<SEQ * BATCH, 256, 0, stream>>>(X, C, xs);
  k_gemx<<<dim3(64, 16), 256, 0, stream>>>(xs, wx1, bc1, G1sw);
  k_mega<<<256, 256, 0, stream>>>(G1sw, wh1, wx2, wh2, bc2, h1ex, h2ex, c0, c0_y, hTy,
                                  flags);
  float* partial = (float*)G1sw;  // G1sw dead after k_mega; 16.4MB needed
  k_final<<<dim3(125, 2), 256, 0, stream>>>((const short*)hTy, W3, partial);
  k_fincomb<<<dim3(125, 64), 256, 0, stream>>>(partial, b2, (float*)d_out);
}

// Round 4
// 3101.102 us; speedup vs baseline: 2.7903x; 1.8682x over previous
//
#include <hip/hip_runtime.h>
#include <hip/hip_bf16.h>

// TextRNN: embed -> 2-layer LSTM (B=64,T=256,H=1024) -> proj 32000, f32 out.
// R4: same structure as R3 (one persistent k_mega, 257 rounds, distributed
// barrier w/ per-group aggregator, h via L3-resident ring w/ relaxed agent
// atomics, gate exchange via shuffles). ONE FIX: weight arrays fully
// static-indexed (full unroll) so they live in VGPRs, not scratch.
// R3 bug: '#pragma unroll 8' left runtime indices -> 26GB scratch traffic.

typedef __attribute__((ext_vector_type(8))) short s16x8;
typedef __attribute__((ext_vector_type(4))) float f32x4;
typedef unsigned long long u64;

#define N_CLASS 32000
#define EMB 512
#define HID 1024
#define BATCH 64
#define SEQ 256
#define NG4 4096

static __device__ __forceinline__ short f2bf(float x) {
  __hip_bfloat16 h = __float2bfloat16(x);
  return *reinterpret_cast<short*>(&h);
}
static __device__ __forceinline__ float bf2f(short x) {
  __hip_bfloat16 h = *reinterpret_cast<__hip_bfloat16*>(&x);
  return __bfloat162float(h);
}
static __device__ __forceinline__ float fsigm(float x) {
  return __builtin_amdgcn_rcpf(1.f + __expf(-x));
}
static __device__ __forceinline__ float ftanh(float x) {
  return 2.f * __builtin_amdgcn_rcpf(1.f + __expf(-2.f * x)) - 1.f;
}

// ---- weight conversion to swizzled bf16 B-layout: sw[((k>>3)*4096+n)*8+(k&7)]
__global__ void k_conv_w4(const float* __restrict__ Wg, const float* __restrict__ Wi,
                          const float* __restrict__ Wf, const float* __restrict__ Wo,
                          short* __restrict__ sw, int K) {
  int i = blockIdx.x * 256 + threadIdx.x;
  int k8 = i >> 10, j = i & 1023;
  if (k8 >= (K >> 3)) return;
  const float* W = blockIdx.z == 0 ? Wg : blockIdx.z == 1 ? Wi : blockIdx.z == 2 ? Wf : Wo;
  s16x8 v;
#pragma unroll
  for (int e = 0; e < 8; ++e) v[e] = f2bf(W[(size_t)(k8 * 8 + e) * 1024 + j]);
  *(s16x8*)(sw + ((size_t)k8 * NG4 + blockIdx.z * 1024 + j) * 8) = v;
}

__global__ void k_bcat(const float* __restrict__ b0, const float* __restrict__ b1,
                       const float* __restrict__ b2, const float* __restrict__ b3,
                       float* __restrict__ dst) {
  int i = blockIdx.x * 256 + threadIdx.x;  // 4096
  const float* s = (i >> 10) == 0 ? b0 : (i >> 10) == 1 ? b1 : (i >> 10) == 2 ? b2 : b3;
  dst[i] = s[i & 1023];
}

__global__ void k_f2bf(const float* __restrict__ src, short* __restrict__ dst, int n) {
  int i = blockIdx.x * 256 + threadIdx.x;
  if (i < n) dst[i] = f2bf(src[i]);
}

// ---- embedding gather --------------------------------------------------------
__global__ void k_embed(const int* __restrict__ X, const float* __restrict__ C,
                        short* __restrict__ xs) {
  int r = blockIdx.x;
  int t = r >> 6, b = r & 63;
  int idx = X[b * SEQ + t];
  const float* src = C + (size_t)idx * EMB;
  float2 v = *(const float2*)(src + threadIdx.x * 2);
  short* dst = xs + (size_t)r * EMB + threadIdx.x * 2;
  dst[0] = f2bf(v.x);
  dst[1] = f2bf(v.y);
}

// ---- G1 pre-GEMM: Gsw (bf16 packed u64) = xs@Wx1 + b1 ------------------------
__global__ __launch_bounds__(256) void k_gemx(const short* __restrict__ A,
                                              const short* __restrict__ Bsw,
                                              const float* __restrict__ bias,
                                              u64* __restrict__ Gsw) {
  __shared__ short lds[4096 * 8];  // 64KB B panel (K=512 x BN=64)
  int tid = threadIdx.x;
  int n0 = blockIdx.x * 64;
  for (int cid = tid; cid < 4096; cid += 256) {
    int k8 = cid >> 6, nl = cid & 63;
    *(s16x8*)(lds + (size_t)cid * 8) = *(const s16x8*)(Bsw + ((size_t)k8 * NG4 + n0 + nl) * 8);
  }
  __syncthreads();
  int lane = tid & 63, wid = tid >> 6;
  int l15 = lane & 15, l4 = lane >> 4;
  int ms = wid >> 1, ns = wid & 1;
  for (int m0 = blockIdx.y * 64; m0 < SEQ * BATCH; m0 += gridDim.y * 64) {
    f32x4 acc[2][2];
#pragma unroll
    for (int i = 0; i < 2; ++i)
#pragma unroll
      for (int j = 0; j < 2; ++j) acc[i][j] = (f32x4){0.f, 0.f, 0.f, 0.f};
    const short* a0p = A + (size_t)(m0 + ms * 32 + l15) * EMB + l4 * 8;
    const short* a1p = a0p + (size_t)16 * EMB;
#pragma unroll 4
    for (int kc = 0; kc < 16; ++kc) {
      s16x8 av0 = *(const s16x8*)(a0p + kc * 32);
      s16x8 av1 = *(const s16x8*)(a1p + kc * 32);
#pragma unroll
      for (int j = 0; j < 2; ++j) {
        s16x8 bv = *(const s16x8*)(lds + (size_t)((kc * 4 + l4) * 64 + ns * 32 + j * 16 + l15) * 8);
        acc[0][j] = __builtin_amdgcn_mfma_f32_16x16x32_bf16(av0, bv, acc[0][j], 0, 0, 0);
        acc[1][j] = __builtin_amdgcn_mfma_f32_16x16x32_bf16(av1, bv, acc[1][j], 0, 0, 0);
      }
    }
    int t = m0 >> 6;
#pragma unroll
    for (int i = 0; i < 2; ++i)
#pragma unroll
      for (int j = 0; j < 2; ++j) {
        int grp = ms * 2 + i;
        int colg = n0 + ns * 32 + j * 16 + l15;
        float bv = bias[colg];
        int q = colg >> 10, nslc = (colg >> 4) & 63;
        u64 pk = 0;
#pragma unroll
        for (int e = 0; e < 4; ++e)
          pk |= (u64)(unsigned short)f2bf(acc[i][j][e] + bv) << (16 * e);
        size_t slot = ((((size_t)t * 4 + grp) * 64 + nslc) * 4 + q) * 64 + l4 * 16 + l15;
        Gsw[slot] = pk;
      }
  }
}

// ---- persistent 2-layer recurrence ------------------------------------------
__global__ __launch_bounds__(256, 1) void k_mega(
    const u64* __restrict__ G64, const short* __restrict__ Wh1sw,
    const short* __restrict__ Wx2sw, const short* __restrict__ Wh2sw,
    const float* __restrict__ bc2, u64* __restrict__ h1ex, u64* __restrict__ h2ex,
    const float* __restrict__ c0, const float* __restrict__ c0y,
    u64* __restrict__ hTy, unsigned* __restrict__ flags) {
  __shared__ short a_lds[2 * 16 * 1024];  // 64KB: A1 | A2, XOR-swizzled rows
  const int tid = threadIdx.x;
  const int lane = tid & 63, wv = tid >> 6;
  const int l15 = lane & 15, l4 = lane >> 4;
  const int group = (int)blockIdx.x >> 6, nsl = (int)blockIdx.x & 63;
  const int col = (l15 >> 2) * 1024 + nsl * 16 + wv * 4 + (l15 & 3);

  // Weight slices in VGPRs: 96 x s16x8 = 384 VGPR. MUST be static-indexed
  // everywhere (rule #20) -> full unroll, no partial.
  s16x8 b1r[32], bxr[32], b2r[32];
#pragma unroll
  for (int kc = 0; kc < 32; ++kc) {
    size_t o = ((size_t)(kc * 4 + l4) * NG4 + col) * 8;
    b1r[kc] = *(const s16x8*)(Wh1sw + o);
  }
#pragma unroll
  for (int kc = 0; kc < 32; ++kc) {
    size_t o = ((size_t)(kc * 4 + l4) * NG4 + col) * 8;
    bxr[kc] = *(const s16x8*)(Wx2sw + o);
  }
#pragma unroll
  for (int kc = 0; kc < 32; ++kc) {
    size_t o = ((size_t)(kc * 4 + l4) * NG4 + col) * 8;
    b2r[kc] = *(const s16x8*)(Wh2sw + o);
  }
  const float bias2 = bc2[col];
  float c1v[4], c2v[4];
#pragma unroll
  for (int e = 0; e < 4; ++e) {
    int gi = (group * 16 + l4 * 4 + e) * HID + nsl * 16 + wv * 4 + (l15 & 3);
    c1v[e] = c0[gi];
    c2v[e] = c0y[gi];
  }
  unsigned* arr = flags;          // [4][64] slots, stride 32 u32 (128B)
  unsigned* done = flags + 8192;  // [4] lines, stride 32 u32
  const int srow = tid >> 4, scol = tid & 15;
  const int exrow = (group * 16 + srow) * 256;
  const size_t gbase =
      (((size_t)group * 64 + nsl) * 4 + (l15 >> 2)) * 64 + l4 * 16 + wv * 4 + (l15 & 3);
  u64 gcur = G64[gbase], gnext = 0;
  const int gsrc = l4 * 16 + (l15 & 3);
  const int psrc = ((l15 >> 2) << 4) + ((l15 & 3) << 2);
  const int swzm = (l15 & 7) << 4;
  const int abase = l15 * 2048 + l4 * 16;

  for (int r = 0; r <= 256; ++r) {
    if (r > 0) {
      if (nsl == 0) {
        if (tid < 64) {
          unsigned* p = arr + ((group << 6) + tid) * 32;
          while (__hip_atomic_load(p, __ATOMIC_RELAXED, __HIP_MEMORY_SCOPE_AGENT) <
                 (unsigned)r)
            __builtin_amdgcn_s_sleep(2);
        }
        if (tid == 0)
          __hip_atomic_store(done + group * 32, (unsigned)r, __ATOMIC_RELAXED,
                             __HIP_MEMORY_SCOPE_AGENT);
      } else if (tid == 0) {
        while (__hip_atomic_load(done + group * 32, __ATOMIC_RELAXED,
                                 __HIP_MEMORY_SCOPE_AGENT) < (unsigned)r)
          __builtin_amdgcn_s_sleep(2);
      }
      __syncthreads();
      asm volatile("" ::: "memory");
    }
    {  // stage A1 = h1(r-1), A2 = h2(r-2) from ring slot (r+1)&1
      const int slot = (r + 1) & 1;
      const u64* s1 = h1ex + slot * 16384 + exrow;
      const u64* s2 = h2ex + slot * 16384 + exrow;
#pragma unroll 4
      for (int i = 0; i < 16; ++i) {
        int chunk = scol + (i << 4);
        u64 v1 = __hip_atomic_load(s1 + chunk, __ATOMIC_RELAXED, __HIP_MEMORY_SCOPE_AGENT);
        u64 v2 = __hip_atomic_load(s2 + chunk, __ATOMIC_RELAXED, __HIP_MEMORY_SCOPE_AGENT);
        int bo = (srow * 2048 + chunk * 8) ^ ((srow & 7) << 4);
        *(u64*)((char*)a_lds + bo) = v1;
        *(u64*)((char*)a_lds + 32768 + bo) = v2;
      }
    }
    __syncthreads();
    if (r + 1 < 256) gnext = G64[gbase + (size_t)(r + 1) * 65536];

    if (r < 256) {  // ---- layer 1: gates = G1(r) + h1(r-1)@Wh1 ----
      f32x4 ch0, ch1;
#pragma unroll
      for (int e = 0; e < 4; ++e)
        ch0[e] = __uint_as_float((unsigned)((gcur >> (16 * e)) & 0xffffu) << 16);
      ch1 = (f32x4){0.f, 0.f, 0.f, 0.f};
#pragma unroll
      for (int kc = 0; kc < 32; kc += 2) {
        s16x8 a0 = *(const s16x8*)((const char*)a_lds + ((abase + (kc + 0) * 64) ^ swzm));
        s16x8 a1 = *(const s16x8*)((const char*)a_lds + ((abase + (kc + 1) * 64) ^ swzm));
        ch0 = __builtin_amdgcn_mfma_f32_16x16x32_bf16(a0, b1r[kc + 0], ch0, 0, 0, 0);
        ch1 = __builtin_amdgcn_mfma_f32_16x16x32_bf16(a1, b1r[kc + 1], ch1, 0, 0, 0);
      }
      f32x4 acc = ch0 + ch1;
      float hh0, hh1, hh2, hh3;
#pragma unroll
      for (int e = 0; e < 4; ++e) {
        float xg = __shfl(acc[e], gsrc + 0);
        float xi = __shfl(acc[e], gsrc + 4);
        float xf = __shfl(acc[e], gsrc + 8);
        float xo = __shfl(acc[e], gsrc + 12);
        float cn = c1v[e] * fsigm(xf) + ftanh(xg) * fsigm(xi);
        c1v[e] = cn;
        float hv = ftanh(cn) * fsigm(xo);
        if (e == 0) hh0 = hv;
        else if (e == 1) hh1 = hv;
        else if (e == 2) hh2 = hv;
        else hh3 = hv;
      }
      int rr = l15 >> 2;
      float hexp = rr == 0 ? hh0 : rr == 1 ? hh1 : rr == 2 ? hh2 : hh3;
      float p0 = __shfl(hexp, psrc + 0);
      float p1 = __shfl(hexp, psrc + 1);
      float p2 = __shfl(hexp, psrc + 2);
      float p3 = __shfl(hexp, psrc + 3);
      if (lane < 16) {
        u64 pk = (u64)(unsigned short)f2bf(p0) | ((u64)(unsigned short)f2bf(p1) << 16) |
                 ((u64)(unsigned short)f2bf(p2) << 32) |
                 ((u64)(unsigned short)f2bf(p3) << 48);
        __hip_atomic_store(h1ex + (r & 1) * 16384 + (group * 16 + lane) * 256 + nsl * 4 + wv,
                           pk, __ATOMIC_RELAXED, __HIP_MEMORY_SCOPE_AGENT);
      }
    }

    if (r >= 1) {  // ---- layer 2: gates = b2 + h1(r-1)@Wx2 + h2(r-2)@Wh2 ----
      f32x4 ch0 = (f32x4){bias2, bias2, bias2, bias2};
      f32x4 ch1 = (f32x4){0.f, 0.f, 0.f, 0.f};
#pragma unroll
      for (int kc = 0; kc < 32; ++kc) {
        int o0 = (abase + kc * 64) ^ swzm;
        s16x8 a10 = *(const s16x8*)((const char*)a_lds + o0);
        s16x8 a20 = *(const s16x8*)((const char*)a_lds + 32768 + o0);
        ch0 = __builtin_amdgcn_mfma_f32_16x16x32_bf16(a10, bxr[kc], ch0, 0, 0, 0);
        ch1 = __builtin_amdgcn_mfma_f32_16x16x32_bf16(a20, b2r[kc], ch1, 0, 0, 0);
      }
      f32x4 acc = ch0 + ch1;
      float hh0, hh1, hh2, hh3;
#pragma unroll
      for (int e = 0; e < 4; ++e) {
        float xg = __shfl(acc[e], gsrc + 0);
        float xi = __shfl(acc[e], gsrc + 4);
        float xf = __shfl(acc[e], gsrc + 8);
        float xo = __shfl(acc[e], gsrc + 12);
        float cn = c2v[e] * fsigm(xf) + ftanh(xg) * fsigm(xi);
        c2v[e] = cn;
        float hv = ftanh(cn) * fsigm(xo);
        if (e == 0) hh0 = hv;
        else if (e == 1) hh1 = hv;
        else if (e == 2) hh2 = hv;
        else hh3 = hv;
      }
      int rr = l15 >> 2;
      float hexp = rr == 0 ? hh0 : rr == 1 ? hh1 : rr == 2 ? hh2 : hh3;
      float p0 = __shfl(hexp, psrc + 0);
      float p1 = __shfl(hexp, psrc + 1);
      float p2 = __shfl(hexp, psrc + 2);
      float p3 = __shfl(hexp, psrc + 3);
      if (lane < 16) {
        u64 pk = (u64)(unsigned short)f2bf(p0) | ((u64)(unsigned short)f2bf(p1) << 16) |
                 ((u64)(unsigned short)f2bf(p2) << 32) |
                 ((u64)(unsigned short)f2bf(p3) << 48);
        int idx = (group * 16 + lane) * 256 + nsl * 4 + wv;
        if (r < 256)
          __hip_atomic_store(h2ex + (r & 1) * 16384 + idx, pk, __ATOMIC_RELAXED,
                             __HIP_MEMORY_SCOPE_AGENT);
        else
          hTy[idx] = pk;  // h2(255) = hT_y
      }
    }

    if (r < 256) {
      asm volatile("s_waitcnt vmcnt(0)" ::: "memory");
      __syncthreads();
      if (tid == 0)
        __hip_atomic_store(arr + ((group << 6) + nsl) * 32, (unsigned)(r + 1),
                           __ATOMIC_RELAXED, __HIP_MEMORY_SCOPE_AGENT);
    }
    gcur = gnext;
  }
}

// ---- final projection, split-K=2 --------------------------------------------
__global__ __launch_bounds__(256) void k_final(const short* __restrict__ hT,
                                               const float* __restrict__ W3,
                                               float* __restrict__ partial) {
  __shared__ float hst[64][64];
  int tid = threadIdx.x;
  int n = blockIdx.x * 256 + tid;
  int kbase = blockIdx.y * 512;
  float acc[64];
#pragma unroll
  for (int i = 0; i < 64; ++i) acc[i] = 0.f;
  int bb = tid >> 2, part = tid & 3;
  for (int kc = 0; kc < 512; kc += 64) {
    __syncthreads();
    s16x8 v0 = *(const s16x8*)(hT + bb * HID + kbase + kc + part * 16);
    s16x8 v1 = *(const s16x8*)(hT + bb * HID + kbase + kc + part * 16 + 8);
#pragma unroll
    for (int e = 0; e < 8; ++e) {
      hst[part * 16 + e][bb] = bf2f(v0[e]);
      hst[part * 16 + 8 + e][bb] = bf2f(v1[e]);
    }
    __syncthreads();
    for (int k = 0; k < 64; ++k) {
      float wv = W3[(size_t)(kbase + kc + k) * N_CLASS + n];
      const float4* hp = (const float4*)&hst[k][0];
#pragma unroll
      for (int b4 = 0; b4 < 16; ++b4) {
        float4 h4 = hp[b4];
        acc[b4 * 4 + 0] += h4.x * wv;
        acc[b4 * 4 + 1] += h4.y * wv;
        acc[b4 * 4 + 2] += h4.z * wv;
        acc[b4 * 4 + 3] += h4.w * wv;
      }
    }
  }
#pragma unroll
  for (int b = 0; b < 64; ++b)
    partial[((size_t)blockIdx.y * 64 + b) * N_CLASS + n] = acc[b];
}

__global__ void k_fincomb(const float* __restrict__ partial, const float* __restrict__ b2,
                          float* __restrict__ out) {
  int n = blockIdx.x * 256 + threadIdx.x;
  int b = blockIdx.y;
  out[(size_t)b * N_CLASS + n] =
      partial[(size_t)b * N_CLASS + n] + partial[((size_t)64 + b) * N_CLASS + n] + b2[n];
}

extern "C" void kernel_launch(void* const* d_in, const int* in_sizes, int n_in, void* d_out,
                              int out_size, void* d_ws, size_t ws_size, hipStream_t stream) {
  (void)in_sizes; (void)n_in; (void)out_size; (void)ws_size;
  const int* X = (const int*)d_in[0];
  const float* C = (const float*)d_in[1];
  const float* W1 = (const float*)d_in[2];
  const float* W_xi = (const float*)d_in[3];
  const float* W_xf = (const float*)d_in[4];
  const float* W_xo = (const float*)d_in[5];
  const float* W2 = (const float*)d_in[6];
  const float* W_hi = (const float*)d_in[7];
  const float* W_hf = (const float*)d_in[8];
  const float* W_ho = (const float*)d_in[9];
  const float* b1 = (const float*)d_in[10];
  const float* b_i = (const float*)d_in[11];
  const float* b_f = (const float*)d_in[12];
  const float* b_o = (const float*)d_in[13];
  const float* W1_y = (const float*)d_in[14];
  const float* W_xi_y = (const float*)d_in[15];
  const float* W_xf_y = (const float*)d_in[16];
  const float* W_xo_y = (const float*)d_in[17];
  const float* W2_y = (const float*)d_in[18];
  const float* W_hi_y = (const float*)d_in[19];
  const float* W_hf_y = (const float*)d_in[20];
  const float* W_ho_y = (const float*)d_in[21];
  const float* b1_y = (const float*)d_in[22];
  const float* b_i_y = (const float*)d_in[23];
  const float* b_f_y = (const float*)d_in[24];
  const float* b_o_y = (const float*)d_in[25];
  const float* W3 = (const float*)d_in[26];
  const float* b2 = (const float*)d_in[27];
  const float* h0 = (const float*)d_in[28];
  const float* c0 = (const float*)d_in[29];
  const float* h0_y = (const float*)d_in[30];
  const float* c0_y = (const float*)d_in[31];

  char* w = (char*)d_ws;
  size_t off = 0;
  auto take = [&](size_t bytes) {
    char* p = w + off;
    off += (bytes + 255) & ~(size_t)255;
    return p;
  };
  short* wx1 = (short*)take(64UL * NG4 * 8 * 2);
  short* wh1 = (short*)take(128UL * NG4 * 8 * 2);
  short* wx2 = (short*)take(128UL * NG4 * 8 * 2);
  short* wh2 = (short*)take(128UL * NG4 * 8 * 2);
  short* xs = (short*)take((size_t)SEQ * BATCH * EMB * 2);
  u64* G1sw = (u64*)take((size_t)SEQ * 65536 * 8);  // 134MB; partials alias later
  float* bc1 = (float*)take(NG4 * 4);
  float* bc2 = (float*)take(NG4 * 4);
  u64* h1ex = (u64*)take(2UL * 16384 * 8);
  u64* h2ex = (u64*)take(2UL * 16384 * 8);
  u64* hTy = (u64*)take(16384UL * 8);
  unsigned* flags = (unsigned*)take(65536);

  hipMemsetAsync(flags, 0, 65536, stream);
  k_bcat<<<16, 256, 0, stream>>>(b1, b_i, b_f, b_o, bc1);
  k_bcat<<<16, 256, 0, stream>>>(b1_y, b_i_y, b_f_y, b_o_y, bc2);
  k_f2bf<<<256, 256, 0, stream>>>(h0, (short*)h1ex + 65536, BATCH * HID);
  k_f2bf<<<256, 256, 0, stream>>>(h0_y, (short*)h2ex, BATCH * HID);
  k_conv_w4<<<dim3(256, 1, 4), 256, 0, stream>>>(W1, W_xi, W_xf, W_xo, wx1, 512);
  k_conv_w4<<<dim3(512, 1, 4), 256, 0, stream>>>(W2, W_hi, W_hf, W_ho, wh1, 1024);
  k_conv_w4<<<dim3(512, 1, 4), 256, 0, stream>>>(W1_y, W_xi_y, W_xf_y, W_xo_y, wx2, 1024);
  k_conv_w4<<<dim3(512, 1, 4), 256, 0, stream>>>(W2_y, W_hi_y, W_hf_y, W_ho_y, wh2, 1024);
  k_embed<<<SEQ * BATCH, 256, 0, stream>>>(X, C, xs);
  k_gemx<<<dim3(64, 16), 256, 0, stream>>>(xs, wx1, bc1, G1sw);
  k_mega<<<256, 256, 0, stream>>>(G1sw, wh1, wx2, wh2, bc2, h1ex, h2ex, c0, c0_y, hTy,
                                  flags);
  float* partial = (float*)G1sw;
  k_final<<<dim3(125, 2), 256, 0, stream>>>((const short*)hTy, W3, partial);
  k_fincomb<<<dim3(125, 64), 256, 0, stream>>>(partial, b2, (float*)d_out);
}

// Round 5
// 2430.795 us; speedup vs baseline: 3.5597x; 1.2758x over previous
//
#include <hip/hip_runtime.h>
#include <hip/hip_bf16.h>

// TextRNN: embed -> 2-layer LSTM (B=64,T=256,H=1024) -> proj 32000, f32 out.
// R5: k_mega split-K across wave pairs. 512 thr = 8 waves: waves 0-3 K-low,
// 4-7 K-high. Per-thread weights 48 x s16x8 = 192 VGPR (was 384 -> didn't
// fit -> compiler re-read from L3 every round). Partial-sum exchange via LDS.
// Waves 0-3: layer-1 act/c1/h1-store; waves 4-7: layer-2 act/c2/h2-store.
// Barrier (per-group aggregator, relaxed agent atomics) unchanged from R4.

typedef __attribute__((ext_vector_type(8))) short s16x8;
typedef __attribute__((ext_vector_type(4))) float f32x4;
typedef unsigned long long u64;

#define N_CLASS 32000
#define EMB 512
#define HID 1024
#define BATCH 64
#define SEQ 256
#define NG4 4096

static __device__ __forceinline__ short f2bf(float x) {
  __hip_bfloat16 h = __float2bfloat16(x);
  return *reinterpret_cast<short*>(&h);
}
static __device__ __forceinline__ float bf2f(short x) {
  __hip_bfloat16 h = *reinterpret_cast<__hip_bfloat16*>(&x);
  return __bfloat162float(h);
}
static __device__ __forceinline__ float fsigm(float x) {
  return __builtin_amdgcn_rcpf(1.f + __expf(-x));
}
static __device__ __forceinline__ float ftanh(float x) {
  return 2.f * __builtin_amdgcn_rcpf(1.f + __expf(-2.f * x)) - 1.f;
}

// ---- weight conversion to swizzled bf16 B-layout: sw[((k>>3)*4096+n)*8+(k&7)]
__global__ void k_conv_w4(const float* __restrict__ Wg, const float* __restrict__ Wi,
                          const float* __restrict__ Wf, const float* __restrict__ Wo,
                          short* __restrict__ sw, int K) {
  int i = blockIdx.x * 256 + threadIdx.x;
  int k8 = i >> 10, j = i & 1023;
  if (k8 >= (K >> 3)) return;
  const float* W = blockIdx.z == 0 ? Wg : blockIdx.z == 1 ? Wi : blockIdx.z == 2 ? Wf : Wo;
  s16x8 v;
#pragma unroll
  for (int e = 0; e < 8; ++e) v[e] = f2bf(W[(size_t)(k8 * 8 + e) * 1024 + j]);
  *(s16x8*)(sw + ((size_t)k8 * NG4 + blockIdx.z * 1024 + j) * 8) = v;
}

__global__ void k_bcat(const float* __restrict__ b0, const float* __restrict__ b1,
                       const float* __restrict__ b2, const float* __restrict__ b3,
                       float* __restrict__ dst) {
  int i = blockIdx.x * 256 + threadIdx.x;  // 4096
  const float* s = (i >> 10) == 0 ? b0 : (i >> 10) == 1 ? b1 : (i >> 10) == 2 ? b2 : b3;
  dst[i] = s[i & 1023];
}

__global__ void k_f2bf(const float* __restrict__ src, short* __restrict__ dst, int n) {
  int i = blockIdx.x * 256 + threadIdx.x;
  if (i < n) dst[i] = f2bf(src[i]);
}

// ---- embedding gather --------------------------------------------------------
__global__ void k_embed(const int* __restrict__ X, const float* __restrict__ C,
                        short* __restrict__ xs) {
  int r = blockIdx.x;
  int t = r >> 6, b = r & 63;
  int idx = X[b * SEQ + t];
  const float* src = C + (size_t)idx * EMB;
  float2 v = *(const float2*)(src + threadIdx.x * 2);
  short* dst = xs + (size_t)r * EMB + threadIdx.x * 2;
  dst[0] = f2bf(v.x);
  dst[1] = f2bf(v.y);
}

// ---- G1 pre-GEMM: Gsw (bf16 packed u64) = xs@Wx1 + b1 ------------------------
__global__ __launch_bounds__(256) void k_gemx(const short* __restrict__ A,
                                              const short* __restrict__ Bsw,
                                              const float* __restrict__ bias,
                                              u64* __restrict__ Gsw) {
  __shared__ short lds[4096 * 8];  // 64KB B panel (K=512 x BN=64)
  int tid = threadIdx.x;
  int n0 = blockIdx.x * 64;
  for (int cid = tid; cid < 4096; cid += 256) {
    int k8 = cid >> 6, nl = cid & 63;
    *(s16x8*)(lds + (size_t)cid * 8) = *(const s16x8*)(Bsw + ((size_t)k8 * NG4 + n0 + nl) * 8);
  }
  __syncthreads();
  int lane = tid & 63, wid = tid >> 6;
  int l15 = lane & 15, l4 = lane >> 4;
  int ms = wid >> 1, ns = wid & 1;
  for (int m0 = blockIdx.y * 64; m0 < SEQ * BATCH; m0 += gridDim.y * 64) {
    f32x4 acc[2][2];
#pragma unroll
    for (int i = 0; i < 2; ++i)
#pragma unroll
      for (int j = 0; j < 2; ++j) acc[i][j] = (f32x4){0.f, 0.f, 0.f, 0.f};
    const short* a0p = A + (size_t)(m0 + ms * 32 + l15) * EMB + l4 * 8;
    const short* a1p = a0p + (size_t)16 * EMB;
#pragma unroll 4
    for (int kc = 0; kc < 16; ++kc) {
      s16x8 av0 = *(const s16x8*)(a0p + kc * 32);
      s16x8 av1 = *(const s16x8*)(a1p + kc * 32);
#pragma unroll
      for (int j = 0; j < 2; ++j) {
        s16x8 bv = *(const s16x8*)(lds + (size_t)((kc * 4 + l4) * 64 + ns * 32 + j * 16 + l15) * 8);
        acc[0][j] = __builtin_amdgcn_mfma_f32_16x16x32_bf16(av0, bv, acc[0][j], 0, 0, 0);
        acc[1][j] = __builtin_amdgcn_mfma_f32_16x16x32_bf16(av1, bv, acc[1][j], 0, 0, 0);
      }
    }
    int t = m0 >> 6;
#pragma unroll
    for (int i = 0; i < 2; ++i)
#pragma unroll
      for (int j = 0; j < 2; ++j) {
        int grp = ms * 2 + i;
        int colg = n0 + ns * 32 + j * 16 + l15;
        float bv = bias[colg];
        int q = colg >> 10, nslc = (colg >> 4) & 63;
        u64 pk = 0;
#pragma unroll
        for (int e = 0; e < 4; ++e)
          pk |= (u64)(unsigned short)f2bf(acc[i][j][e] + bv) << (16 * e);
        size_t slot = ((((size_t)t * 4 + grp) * 64 + nslc) * 4 + q) * 64 + l4 * 16 + l15;
        Gsw[slot] = pk;
      }
  }
}

// ---- persistent 2-layer recurrence, split-K wave pairs -----------------------
__global__ __launch_bounds__(512, 2) void k_mega(
    const u64* __restrict__ G64, const short* __restrict__ Wh1sw,
    const short* __restrict__ Wx2sw, const short* __restrict__ Wh2sw,
    const float* __restrict__ bc2, u64* __restrict__ h1ex, u64* __restrict__ h2ex,
    const float* __restrict__ c0, const float* __restrict__ c0y,
    u64* __restrict__ hTy, unsigned* __restrict__ flags) {
  __shared__ short a_lds[2 * 16 * 1024];  // 64KB: A1 | A2, XOR-swizzled rows
  __shared__ f32x4 xch[8][64];            // 8KB partial-sum exchange
  const int tid = threadIdx.x;
  const int lane = tid & 63, W = tid >> 6;
  const int wv = W & 3, khalf = W >> 2;
  const int l15 = lane & 15, l4 = lane >> 4;
  const int group = (int)blockIdx.x >> 6, nsl = (int)blockIdx.x & 63;
  const int col = (l15 >> 2) * 1024 + nsl * 16 + wv * 4 + (l15 & 3);

  // 48 x s16x8 = 192 VGPR of weights; static indices only (rule #20).
  s16x8 b1r[16], bxr[16], b2r[16];
#pragma unroll
  for (int j = 0; j < 16; ++j) {
    size_t o = ((size_t)((khalf * 16 + j) * 4 + l4) * NG4 + col) * 8;
    b1r[j] = *(const s16x8*)(Wh1sw + o);
  }
#pragma unroll
  for (int j = 0; j < 16; ++j) {
    size_t o = ((size_t)((khalf * 16 + j) * 4 + l4) * NG4 + col) * 8;
    bxr[j] = *(const s16x8*)(Wx2sw + o);
  }
#pragma unroll
  for (int j = 0; j < 16; ++j) {
    size_t o = ((size_t)((khalf * 16 + j) * 4 + l4) * NG4 + col) * 8;
    b2r[j] = *(const s16x8*)(Wh2sw + o);
  }
  const float bias2 = bc2[col];
  float cv[4];  // c1 on waves 0-3, c2 on waves 4-7
#pragma unroll
  for (int e = 0; e < 4; ++e) {
    int gi = (group * 16 + l4 * 4 + e) * HID + nsl * 16 + wv * 4 + (l15 & 3);
    cv[e] = (W < 4 ? c0 : c0y)[gi];
  }
  unsigned* arr = flags;          // [4][64] slots, stride 32 u32 (128B)
  unsigned* done = flags + 8192;  // [4] lines, stride 32 u32
  const int srow = tid >> 5, sc5 = tid & 31;
  const int exrow = (group * 16 + srow) * 256;
  const size_t gbase =
      (((size_t)group * 64 + nsl) * 4 + (l15 >> 2)) * 64 + l4 * 16 + wv * 4 + (l15 & 3);
  u64 gcur = (W < 4) ? G64[gbase] : 0;
  u64 gnext = 0;
  const int gsrc = l4 * 16 + (l15 & 3);
  const int psrc = ((l15 >> 2) << 4) + ((l15 & 3) << 2);
  const int swzm = (l15 & 7) << 4;
  const int abase = l15 * 2048 + khalf * 1024 + l4 * 16;

  for (int r = 0; r <= 256; ++r) {
    if (r > 0) {
      if (nsl == 0) {
        if (tid < 64) {
          unsigned* p = arr + ((group << 6) + tid) * 32;
          while (__hip_atomic_load(p, __ATOMIC_RELAXED, __HIP_MEMORY_SCOPE_AGENT) <
                 (unsigned)r)
            __builtin_amdgcn_s_sleep(2);
        }
        if (tid == 0)
          __hip_atomic_store(done + group * 32, (unsigned)r, __ATOMIC_RELAXED,
                             __HIP_MEMORY_SCOPE_AGENT);
      } else if (tid == 0) {
        while (__hip_atomic_load(done + group * 32, __ATOMIC_RELAXED,
                                 __HIP_MEMORY_SCOPE_AGENT) < (unsigned)r)
          __builtin_amdgcn_s_sleep(2);
      }
      __syncthreads();
      asm volatile("" ::: "memory");
    }
    // prefetch G(r+1) early (no dependency on the ring)
    if (W < 4 && r + 1 < 256) gnext = G64[gbase + (size_t)(r + 1) * 65536];
    {  // stage A1 = h1(r-1), A2 = h2(r-2) from ring slot (r+1)&1
      const int slot = (r + 1) & 1;
      const u64* s1 = h1ex + slot * 16384 + exrow;
      const u64* s2 = h2ex + slot * 16384 + exrow;
#pragma unroll
      for (int i = 0; i < 8; ++i) {
        int chunk = sc5 + (i << 5);
        u64 v1 = __hip_atomic_load(s1 + chunk, __ATOMIC_RELAXED, __HIP_MEMORY_SCOPE_AGENT);
        u64 v2 = __hip_atomic_load(s2 + chunk, __ATOMIC_RELAXED, __HIP_MEMORY_SCOPE_AGENT);
        int bo = (srow * 2048 + chunk * 8) ^ ((srow & 7) << 4);
        *(u64*)((char*)a_lds + bo) = v1;
        *(u64*)((char*)a_lds + 32768 + bo) = v2;
      }
    }
    __syncthreads();

    // ---- MFMA: 3 chains (L1, L2-x, L2-h), 16 deep each (this wave's K half)
    f32x4 p1, p2a, p2b;
    if (W < 4) {
#pragma unroll
      for (int e = 0; e < 4; ++e)
        p1[e] = __uint_as_float((unsigned)((gcur >> (16 * e)) & 0xffffu) << 16);
      p2a = (f32x4){0.f, 0.f, 0.f, 0.f};
    } else {
      p1 = (f32x4){0.f, 0.f, 0.f, 0.f};
      p2a = (f32x4){bias2, bias2, bias2, bias2};
    }
    p2b = (f32x4){0.f, 0.f, 0.f, 0.f};
#pragma unroll
    for (int j = 0; j < 16; ++j) {
      int o = (abase + j * 64) ^ swzm;
      s16x8 a1 = *(const s16x8*)((const char*)a_lds + o);
      s16x8 a2 = *(const s16x8*)((const char*)a_lds + 32768 + o);
      p1 = __builtin_amdgcn_mfma_f32_16x16x32_bf16(a1, b1r[j], p1, 0, 0, 0);
      p2a = __builtin_amdgcn_mfma_f32_16x16x32_bf16(a1, bxr[j], p2a, 0, 0, 0);
      p2b = __builtin_amdgcn_mfma_f32_16x16x32_bf16(a2, b2r[j], p2b, 0, 0, 0);
    }
    f32x4 p2 = p2a + p2b;
    // ---- cross-wave-pair partial exchange
    if (W < 4) {
      if (r >= 1) xch[W][lane] = p2;
    } else {
      if (r < 256) xch[W][lane] = p1;
    }
    __syncthreads();

    if (W < 4) {
      if (r < 256) {  // layer-1 activation, h1(r)
        f32x4 po = xch[W + 4][lane];
        f32x4 acc = p1 + po;
        float hh0, hh1, hh2, hh3;
#pragma unroll
        for (int e = 0; e < 4; ++e) {
          float xg = __shfl(acc[e], gsrc + 0);
          float xi = __shfl(acc[e], gsrc + 4);
          float xf = __shfl(acc[e], gsrc + 8);
          float xo = __shfl(acc[e], gsrc + 12);
          float cn = cv[e] * fsigm(xf) + ftanh(xg) * fsigm(xi);
          cv[e] = cn;
          float hv = ftanh(cn) * fsigm(xo);
          if (e == 0) hh0 = hv;
          else if (e == 1) hh1 = hv;
          else if (e == 2) hh2 = hv;
          else hh3 = hv;
        }
        int rr = l15 >> 2;
        float hexp = rr == 0 ? hh0 : rr == 1 ? hh1 : rr == 2 ? hh2 : hh3;
        float p0 = __shfl(hexp, psrc + 0);
        float p1s = __shfl(hexp, psrc + 1);
        float p2s = __shfl(hexp, psrc + 2);
        float p3s = __shfl(hexp, psrc + 3);
        if (lane < 16) {
          u64 pk = (u64)(unsigned short)f2bf(p0) | ((u64)(unsigned short)f2bf(p1s) << 16) |
                   ((u64)(unsigned short)f2bf(p2s) << 32) |
                   ((u64)(unsigned short)f2bf(p3s) << 48);
          __hip_atomic_store(
              h1ex + (r & 1) * 16384 + (group * 16 + lane) * 256 + nsl * 4 + wv, pk,
              __ATOMIC_RELAXED, __HIP_MEMORY_SCOPE_AGENT);
        }
      }
    } else {
      if (r >= 1) {  // layer-2 activation, h2(r-1)
        f32x4 po = xch[W - 4][lane];
        f32x4 acc = p2 + po;
        float hh0, hh1, hh2, hh3;
#pragma unroll
        for (int e = 0; e < 4; ++e) {
          float xg = __shfl(acc[e], gsrc + 0);
          float xi = __shfl(acc[e], gsrc + 4);
          float xf = __shfl(acc[e], gsrc + 8);
          float xo = __shfl(acc[e], gsrc + 12);
          float cn = cv[e] * fsigm(xf) + ftanh(xg) * fsigm(xi);
          cv[e] = cn;
          float hv = ftanh(cn) * fsigm(xo);
          if (e == 0) hh0 = hv;
          else if (e == 1) hh1 = hv;
          else if (e == 2) hh2 = hv;
          else hh3 = hv;
        }
        int rr = l15 >> 2;
        float hexp = rr == 0 ? hh0 : rr == 1 ? hh1 : rr == 2 ? hh2 : hh3;
        float p0 = __shfl(hexp, psrc + 0);
        float p1s = __shfl(hexp, psrc + 1);
        float p2s = __shfl(hexp, psrc + 2);
        float p3s = __shfl(hexp, psrc + 3);
        if (lane < 16) {
          u64 pk = (u64)(unsigned short)f2bf(p0) | ((u64)(unsigned short)f2bf(p1s) << 16) |
                   ((u64)(unsigned short)f2bf(p2s) << 32) |
                   ((u64)(unsigned short)f2bf(p3s) << 48);
          int idx = (group * 16 + lane) * 256 + nsl * 4 + wv;
          if (r < 256)
            __hip_atomic_store(h2ex + (r & 1) * 16384 + idx, pk, __ATOMIC_RELAXED,
                               __HIP_MEMORY_SCOPE_AGENT);
          else
            hTy[idx] = pk;  // h2(255) = hT_y
        }
      }
    }

    if (r < 256) {
      asm volatile("s_waitcnt vmcnt(0)" ::: "memory");
      __syncthreads();
      if (tid == 0)
        __hip_atomic_store(arr + ((group << 6) + nsl) * 32, (unsigned)(r + 1),
                           __ATOMIC_RELAXED, __HIP_MEMORY_SCOPE_AGENT);
    }
    gcur = gnext;
  }
}

// ---- final projection, split-K=2 --------------------------------------------
__global__ __launch_bounds__(256) void k_final(const short* __restrict__ hT,
                                               const float* __restrict__ W3,
                                               float* __restrict__ partial) {
  __shared__ float hst[64][64];
  int tid = threadIdx.x;
  int n = blockIdx.x * 256 + tid;
  int kbase = blockIdx.y * 512;
  float acc[64];
#pragma unroll
  for (int i = 0; i < 64; ++i) acc[i] = 0.f;
  int bb = tid >> 2, part = tid & 3;
  for (int kc = 0; kc < 512; kc += 64) {
    __syncthreads();
    s16x8 v0 = *(const s16x8*)(hT + bb * HID + kbase + kc + part * 16);
    s16x8 v1 = *(const s16x8*)(hT + bb * HID + kbase + kc + part * 16 + 8);
#pragma unroll
    for (int e = 0; e < 8; ++e) {
      hst[part * 16 + e][bb] = bf2f(v0[e]);
      hst[part * 16 + 8 + e][bb] = bf2f(v1[e]);
    }
    __syncthreads();
    for (int k = 0; k < 64; ++k) {
      float wv = W3[(size_t)(kbase + kc + k) * N_CLASS + n];
      const float4* hp = (const float4*)&hst[k][0];
#pragma unroll
      for (int b4 = 0; b4 < 16; ++b4) {
        float4 h4 = hp[b4];
        acc[b4 * 4 + 0] += h4.x * wv;
        acc[b4 * 4 + 1] += h4.y * wv;
        acc[b4 * 4 + 2] += h4.z * wv;
        acc[b4 * 4 + 3] += h4.w * wv;
      }
    }
  }
#pragma unroll
  for (int b = 0; b < 64; ++b)
    partial[((size_t)blockIdx.y * 64 + b) * N_CLASS + n] = acc[b];
}

__global__ void k_fincomb(const float* __restrict__ partial, const float* __restrict__ b2,
                          float* __restrict__ out) {
  int n = blockIdx.x * 256 + threadIdx.x;
  int b = blockIdx.y;
  out[(size_t)b * N_CLASS + n] =
      partial[(size_t)b * N_CLASS + n] + partial[((size_t)64 + b) * N_CLASS + n] + b2[n];
}

extern "C" void kernel_launch(void* const* d_in, const int* in_sizes, int n_in, void* d_out,
                              int out_size, void* d_ws, size_t ws_size, hipStream_t stream) {
  (void)in_sizes; (void)n_in; (void)out_size; (void)ws_size;
  const int* X = (const int*)d_in[0];
  const float* C = (const float*)d_in[1];
  const float* W1 = (const float*)d_in[2];
  const float* W_xi = (const float*)d_in[3];
  const float* W_xf = (const float*)d_in[4];
  const float* W_xo = (const float*)d_in[5];
  const float* W2 = (const float*)d_in[6];
  const float* W_hi = (const float*)d_in[7];
  const float* W_hf = (const float*)d_in[8];
  const float* W_ho = (const float*)d_in[9];
  const float* b1 = (const float*)d_in[10];
  const float* b_i = (const float*)d_in[11];
  const float* b_f = (const float*)d_in[12];
  const float* b_o = (const float*)d_in[13];
  const float* W1_y = (const float*)d_in[14];
  const float* W_xi_y = (const float*)d_in[15];
  const float* W_xf_y = (const float*)d_in[16];
  const float* W_xo_y = (const float*)d_in[17];
  const float* W2_y = (const float*)d_in[18];
  const float* W_hi_y = (const float*)d_in[19];
  const float* W_hf_y = (const float*)d_in[20];
  const float* W_ho_y = (const float*)d_in[21];
  const float* b1_y = (const float*)d_in[22];
  const float* b_i_y = (const float*)d_in[23];
  const float* b_f_y = (const float*)d_in[24];
  const float* b_o_y = (const float*)d_in[25];
  const float* W3 = (const float*)d_in[26];
  const float* b2 = (const float*)d_in[27];
  const float* h0 = (const float*)d_in[28];
  const float* c0 = (const float*)d_in[29];
  const float* h0_y = (const float*)d_in[30];
  const float* c0_y = (const float*)d_in[31];

  char* w = (char*)d_ws;
  size_t off = 0;
  auto take = [&](size_t bytes) {
    char* p = w + off;
    off += (bytes + 255) & ~(size_t)255;
    return p;
  };
  short* wx1 = (short*)take(64UL * NG4 * 8 * 2);
  short* wh1 = (short*)take(128UL * NG4 * 8 * 2);
  short* wx2 = (short*)take(128UL * NG4 * 8 * 2);
  short* wh2 = (short*)take(128UL * NG4 * 8 * 2);
  short* xs = (short*)take((size_t)SEQ * BATCH * EMB * 2);
  u64* G1sw = (u64*)take((size_t)SEQ * 65536 * 8);  // 134MB; partials alias later
  float* bc1 = (float*)take(NG4 * 4);
  float* bc2 = (float*)take(NG4 * 4);
  u64* h1ex = (u64*)take(2UL * 16384 * 8);
  u64* h2ex = (u64*)take(2UL * 16384 * 8);
  u64* hTy = (u64*)take(16384UL * 8);
  unsigned* flags = (unsigned*)take(65536);

  hipMemsetAsync(flags, 0, 65536, stream);
  k_bcat<<<16, 256, 0, stream>>>(b1, b_i, b_f, b_o, bc1);
  k_bcat<<<16, 256, 0, stream>>>(b1_y, b_i_y, b_f_y, b_o_y, bc2);
  k_f2bf<<<256, 256, 0, stream>>>(h0, (short*)h1ex + 65536, BATCH * HID);
  k_f2bf<<<256, 256, 0, stream>>>(h0_y, (short*)h2ex, BATCH * HID);
  k_conv_w4<<<dim3(256, 1, 4), 256, 0, stream>>>(W1, W_xi, W_xf, W_xo, wx1, 512);
  k_conv_w4<<<dim3(512, 1, 4), 256, 0, stream>>>(W2, W_hi, W_hf, W_ho, wh1, 1024);
  k_conv_w4<<<dim3(512, 1, 4), 256, 0, stream>>>(W1_y, W_xi_y, W_xf_y, W_xo_y, wx2, 1024);
  k_conv_w4<<<dim3(512, 1, 4), 256, 0, stream>>>(W2_y, W_hi_y, W_hf_y, W_ho_y, wh2, 1024);
  k_embed<<<SEQ * BATCH, 256, 0, stream>>>(X, C, xs);
  k_gemx<<<dim3(64, 16), 256, 0, stream>>>(xs, wx1, bc1, G1sw);
  k_mega<<<256, 512, 0, stream>>>(G1sw, wh1, wx2, wh2, bc2, h1ex, h2ex, c0, c0_y, hTy,
                                  flags);
  float* partial = (float*)G1sw;
  k_final<<<dim3(125, 2), 256, 0, stream>>>((const short*)hTy, W3, partial);
  k_fincomb<<<dim3(125, 64), 256, 0, stream>>>(partial, b2, (float*)d_out);
}

// Round 6
// 2407.024 us; speedup vs baseline: 3.5949x; 1.0099x over previous
//
#include <hip/hip_runtime.h>
#include <hip/hip_bf16.h>

// TextRNN: embed -> 2-layer LSTM (B=64,T=256,H=1024) -> proj 32000, f32 out.
// R6 = R5 (split-K wave pairs, per-group aggregator barrier, L3 h-ring) plus:
//  - amdgpu_waves_per_eu(2,2) + asm-pinned weight regs (defeat remat; the
//    compiler kept choosing 128-VGPR/4-wave and re-reading 100MB/round of
//    weights from L2 -> R5's VGPR_Count=128, FETCH 347MB)
//  - XCD-aware block remap: group g on XCD pair {2g,2g+1}
//  - G(r+1) prefetch issued before the barrier spin (latency hides in spin)

typedef __attribute__((ext_vector_type(8))) short s16x8;
typedef __attribute__((ext_vector_type(4))) float f32x4;
typedef unsigned long long u64;

#define N_CLASS 32000
#define EMB 512
#define HID 1024
#define BATCH 64
#define SEQ 256
#define NG4 4096

#define PIN(v) asm volatile("" : "+v"(v))

static __device__ __forceinline__ short f2bf(float x) {
  __hip_bfloat16 h = __float2bfloat16(x);
  return *reinterpret_cast<short*>(&h);
}
static __device__ __forceinline__ float bf2f(short x) {
  __hip_bfloat16 h = *reinterpret_cast<__hip_bfloat16*>(&x);
  return __bfloat162float(h);
}
static __device__ __forceinline__ float fsigm(float x) {
  return __builtin_amdgcn_rcpf(1.f + __expf(-x));
}
static __device__ __forceinline__ float ftanh(float x) {
  return 2.f * __builtin_amdgcn_rcpf(1.f + __expf(-2.f * x)) - 1.f;
}

// ---- weight conversion to swizzled bf16 B-layout: sw[((k>>3)*4096+n)*8+(k&7)]
__global__ void k_conv_w4(const float* __restrict__ Wg, const float* __restrict__ Wi,
                          const float* __restrict__ Wf, const float* __restrict__ Wo,
                          short* __restrict__ sw, int K) {
  int i = blockIdx.x * 256 + threadIdx.x;
  int k8 = i >> 10, j = i & 1023;
  if (k8 >= (K >> 3)) return;
  const float* W = blockIdx.z == 0 ? Wg : blockIdx.z == 1 ? Wi : blockIdx.z == 2 ? Wf : Wo;
  s16x8 v;
#pragma unroll
  for (int e = 0; e < 8; ++e) v[e] = f2bf(W[(size_t)(k8 * 8 + e) * 1024 + j]);
  *(s16x8*)(sw + ((size_t)k8 * NG4 + blockIdx.z * 1024 + j) * 8) = v;
}

__global__ void k_bcat(const float* __restrict__ b0, const float* __restrict__ b1,
                       const float* __restrict__ b2, const float* __restrict__ b3,
                       float* __restrict__ dst) {
  int i = blockIdx.x * 256 + threadIdx.x;  // 4096
  const float* s = (i >> 10) == 0 ? b0 : (i >> 10) == 1 ? b1 : (i >> 10) == 2 ? b2 : b3;
  dst[i] = s[i & 1023];
}

__global__ void k_f2bf(const float* __restrict__ src, short* __restrict__ dst, int n) {
  int i = blockIdx.x * 256 + threadIdx.x;
  if (i < n) dst[i] = f2bf(src[i]);
}

// ---- embedding gather --------------------------------------------------------
__global__ void k_embed(const int* __restrict__ X, const float* __restrict__ C,
                        short* __restrict__ xs) {
  int r = blockIdx.x;
  int t = r >> 6, b = r & 63;
  int idx = X[b * SEQ + t];
  const float* src = C + (size_t)idx * EMB;
  float2 v = *(const float2*)(src + threadIdx.x * 2);
  short* dst = xs + (size_t)r * EMB + threadIdx.x * 2;
  dst[0] = f2bf(v.x);
  dst[1] = f2bf(v.y);
}

// ---- G1 pre-GEMM: Gsw (bf16 packed u64) = xs@Wx1 + b1 ------------------------
__global__ __launch_bounds__(256) void k_gemx(const short* __restrict__ A,
                                              const short* __restrict__ Bsw,
                                              const float* __restrict__ bias,
                                              u64* __restrict__ Gsw) {
  __shared__ short lds[4096 * 8];  // 64KB B panel (K=512 x BN=64)
  int tid = threadIdx.x;
  int n0 = blockIdx.x * 64;
  for (int cid = tid; cid < 4096; cid += 256) {
    int k8 = cid >> 6, nl = cid & 63;
    *(s16x8*)(lds + (size_t)cid * 8) = *(const s16x8*)(Bsw + ((size_t)k8 * NG4 + n0 + nl) * 8);
  }
  __syncthreads();
  int lane = tid & 63, wid = tid >> 6;
  int l15 = lane & 15, l4 = lane >> 4;
  int ms = wid >> 1, ns = wid & 1;
  for (int m0 = blockIdx.y * 64; m0 < SEQ * BATCH; m0 += gridDim.y * 64) {
    f32x4 acc[2][2];
#pragma unroll
    for (int i = 0; i < 2; ++i)
#pragma unroll
      for (int j = 0; j < 2; ++j) acc[i][j] = (f32x4){0.f, 0.f, 0.f, 0.f};
    const short* a0p = A + (size_t)(m0 + ms * 32 + l15) * EMB + l4 * 8;
    const short* a1p = a0p + (size_t)16 * EMB;
#pragma unroll 4
    for (int kc = 0; kc < 16; ++kc) {
      s16x8 av0 = *(const s16x8*)(a0p + kc * 32);
      s16x8 av1 = *(const s16x8*)(a1p + kc * 32);
#pragma unroll
      for (int j = 0; j < 2; ++j) {
        s16x8 bv = *(const s16x8*)(lds + (size_t)((kc * 4 + l4) * 64 + ns * 32 + j * 16 + l15) * 8);
        acc[0][j] = __builtin_amdgcn_mfma_f32_16x16x32_bf16(av0, bv, acc[0][j], 0, 0, 0);
        acc[1][j] = __builtin_amdgcn_mfma_f32_16x16x32_bf16(av1, bv, acc[1][j], 0, 0, 0);
      }
    }
    int t = m0 >> 6;
#pragma unroll
    for (int i = 0; i < 2; ++i)
#pragma unroll
      for (int j = 0; j < 2; ++j) {
        int grp = ms * 2 + i;
        int colg = n0 + ns * 32 + j * 16 + l15;
        float bv = bias[colg];
        int q = colg >> 10, nslc = (colg >> 4) & 63;
        u64 pk = 0;
#pragma unroll
        for (int e = 0; e < 4; ++e)
          pk |= (u64)(unsigned short)f2bf(acc[i][j][e] + bv) << (16 * e);
        size_t slot = ((((size_t)t * 4 + grp) * 64 + nslc) * 4 + q) * 64 + l4 * 16 + l15;
        Gsw[slot] = pk;
      }
  }
}

// ---- persistent 2-layer recurrence, split-K wave pairs -----------------------
__global__ __launch_bounds__(512) __attribute__((amdgpu_waves_per_eu(2, 2))) void k_mega(
    const u64* __restrict__ G64, const short* __restrict__ Wh1sw,
    const short* __restrict__ Wx2sw, const short* __restrict__ Wh2sw,
    const float* __restrict__ bc2, u64* __restrict__ h1ex, u64* __restrict__ h2ex,
    const float* __restrict__ c0, const float* __restrict__ c0y,
    u64* __restrict__ hTy, unsigned* __restrict__ flags) {
  __shared__ short a_lds[2 * 16 * 1024];  // 64KB: A1 | A2, XOR-swizzled rows
  __shared__ f32x4 xch[8][64];            // 8KB partial-sum exchange
  const int tid = threadIdx.x;
  const int lane = tid & 63, W = tid >> 6;
  const int wv = W & 3, khalf = W >> 2;
  const int l15 = lane & 15, l4 = lane >> 4;
  // XCD-aware remap: group g lives on XCD pair {2g, 2g+1} (bid%8 round-robin)
  const int xcd = (int)blockIdx.x & 7;
  const int group = xcd >> 1;
  const int nsl = ((((int)blockIdx.x >> 3) << 1) | (xcd & 1));
  const int col = (l15 >> 2) * 1024 + nsl * 16 + wv * 4 + (l15 & 3);

  // 48 x s16x8 = 192 VGPR of weights; static indices + asm pin (no remat).
  s16x8 b1r[16], bxr[16], b2r[16];
#pragma unroll
  for (int j = 0; j < 16; ++j) {
    size_t o = ((size_t)((khalf * 16 + j) * 4 + l4) * NG4 + col) * 8;
    b1r[j] = *(const s16x8*)(Wh1sw + o);
    PIN(b1r[j]);
  }
#pragma unroll
  for (int j = 0; j < 16; ++j) {
    size_t o = ((size_t)((khalf * 16 + j) * 4 + l4) * NG4 + col) * 8;
    bxr[j] = *(const s16x8*)(Wx2sw + o);
    PIN(bxr[j]);
  }
#pragma unroll
  for (int j = 0; j < 16; ++j) {
    size_t o = ((size_t)((khalf * 16 + j) * 4 + l4) * NG4 + col) * 8;
    b2r[j] = *(const s16x8*)(Wh2sw + o);
    PIN(b2r[j]);
  }
  const float bias2 = bc2[col];
  float cv[4];  // c1 on waves 0-3, c2 on waves 4-7
#pragma unroll
  for (int e = 0; e < 4; ++e) {
    int gi = (group * 16 + l4 * 4 + e) * HID + nsl * 16 + wv * 4 + (l15 & 3);
    cv[e] = (W < 4 ? c0 : c0y)[gi];
  }
  unsigned* arr = flags;          // [4][64] slots, stride 32 u32 (128B)
  unsigned* done = flags + 8192;  // [4] lines, stride 32 u32
  const int srow = tid >> 5, sc5 = tid & 31;
  const int exrow = (group * 16 + srow) * 256;
  const size_t gbase =
      (((size_t)group * 64 + nsl) * 4 + (l15 >> 2)) * 64 + l4 * 16 + wv * 4 + (l15 & 3);
  u64 gcur = (W < 4) ? G64[gbase] : 0;
  u64 gnext = 0;
  const int gsrc = l4 * 16 + (l15 & 3);
  const int psrc = ((l15 >> 2) << 4) + ((l15 & 3) << 2);
  const int swzm = (l15 & 7) << 4;
  const int abase = l15 * 2048 + khalf * 1024 + l4 * 16;

  for (int r = 0; r <= 256; ++r) {
    // prefetch G(r+1): issued BEFORE the spin so HBM latency hides in it
    if (W < 4 && r + 1 < 256) gnext = G64[gbase + (size_t)(r + 1) * 65536];
    if (r > 0) {
      if (nsl == 0) {
        if (tid < 64) {
          unsigned* p = arr + ((group << 6) + tid) * 32;
          while (__hip_atomic_load(p, __ATOMIC_RELAXED, __HIP_MEMORY_SCOPE_AGENT) <
                 (unsigned)r)
            __builtin_amdgcn_s_sleep(2);
        }
        if (tid == 0)
          __hip_atomic_store(done + group * 32, (unsigned)r, __ATOMIC_RELAXED,
                             __HIP_MEMORY_SCOPE_AGENT);
      } else if (tid == 0) {
        while (__hip_atomic_load(done + group * 32, __ATOMIC_RELAXED,
                                 __HIP_MEMORY_SCOPE_AGENT) < (unsigned)r)
          __builtin_amdgcn_s_sleep(2);
      }
      __syncthreads();
      asm volatile("" ::: "memory");
    }
    {  // stage A1 = h1(r-1), A2 = h2(r-2) from ring slot (r+1)&1
      const int slot = (r + 1) & 1;
      const u64* s1 = h1ex + slot * 16384 + exrow;
      const u64* s2 = h2ex + slot * 16384 + exrow;
#pragma unroll
      for (int i = 0; i < 8; ++i) {
        int chunk = sc5 + (i << 5);
        u64 v1 = __hip_atomic_load(s1 + chunk, __ATOMIC_RELAXED, __HIP_MEMORY_SCOPE_AGENT);
        u64 v2 = __hip_atomic_load(s2 + chunk, __ATOMIC_RELAXED, __HIP_MEMORY_SCOPE_AGENT);
        int bo = (srow * 2048 + chunk * 8) ^ ((srow & 7) << 4);
        *(u64*)((char*)a_lds + bo) = v1;
        *(u64*)((char*)a_lds + 32768 + bo) = v2;
      }
    }
    __syncthreads();

    // ---- MFMA: 3 chains (L1, L2-x, L2-h), 16 deep each (this wave's K half)
    f32x4 p1, p2a, p2b;
    if (W < 4) {
#pragma unroll
      for (int e = 0; e < 4; ++e)
        p1[e] = __uint_as_float((unsigned)((gcur >> (16 * e)) & 0xffffu) << 16);
      p2a = (f32x4){0.f, 0.f, 0.f, 0.f};
    } else {
      p1 = (f32x4){0.f, 0.f, 0.f, 0.f};
      p2a = (f32x4){bias2, bias2, bias2, bias2};
    }
    p2b = (f32x4){0.f, 0.f, 0.f, 0.f};
#pragma unroll
    for (int j = 0; j < 16; ++j) {
      int o = (abase + j * 64) ^ swzm;
      s16x8 a1 = *(const s16x8*)((const char*)a_lds + o);
      s16x8 a2 = *(const s16x8*)((const char*)a_lds + 32768 + o);
      p1 = __builtin_amdgcn_mfma_f32_16x16x32_bf16(a1, b1r[j], p1, 0, 0, 0);
      p2a = __builtin_amdgcn_mfma_f32_16x16x32_bf16(a1, bxr[j], p2a, 0, 0, 0);
      p2b = __builtin_amdgcn_mfma_f32_16x16x32_bf16(a2, b2r[j], p2b, 0, 0, 0);
    }
    f32x4 p2 = p2a + p2b;
    // ---- cross-wave-pair partial exchange
    if (W < 4) {
      if (r >= 1) xch[W][lane] = p2;
    } else {
      if (r < 256) xch[W][lane] = p1;
    }
    __syncthreads();

    if (W < 4) {
      if (r < 256) {  // layer-1 activation, h1(r)
        f32x4 po = xch[W + 4][lane];
        f32x4 acc = p1 + po;
        float hh0, hh1, hh2, hh3;
#pragma unroll
        for (int e = 0; e < 4; ++e) {
          float xg = __shfl(acc[e], gsrc + 0);
          float xi = __shfl(acc[e], gsrc + 4);
          float xf = __shfl(acc[e], gsrc + 8);
          float xo = __shfl(acc[e], gsrc + 12);
          float cn = cv[e] * fsigm(xf) + ftanh(xg) * fsigm(xi);
          cv[e] = cn;
          float hv = ftanh(cn) * fsigm(xo);
          if (e == 0) hh0 = hv;
          else if (e == 1) hh1 = hv;
          else if (e == 2) hh2 = hv;
          else hh3 = hv;
        }
        int rr = l15 >> 2;
        float hexp = rr == 0 ? hh0 : rr == 1 ? hh1 : rr == 2 ? hh2 : hh3;
        float p0 = __shfl(hexp, psrc + 0);
        float p1s = __shfl(hexp, psrc + 1);
        float p2s = __shfl(hexp, psrc + 2);
        float p3s = __shfl(hexp, psrc + 3);
        if (lane < 16) {
          u64 pk = (u64)(unsigned short)f2bf(p0) | ((u64)(unsigned short)f2bf(p1s) << 16) |
                   ((u64)(unsigned short)f2bf(p2s) << 32) |
                   ((u64)(unsigned short)f2bf(p3s) << 48);
          __hip_atomic_store(
              h1ex + (r & 1) * 16384 + (group * 16 + lane) * 256 + nsl * 4 + wv, pk,
              __ATOMIC_RELAXED, __HIP_MEMORY_SCOPE_AGENT);
        }
      }
    } else {
      if (r >= 1) {  // layer-2 activation, h2(r-1)
        f32x4 po = xch[W - 4][lane];
        f32x4 acc = p2 + po;
        float hh0, hh1, hh2, hh3;
#pragma unroll
        for (int e = 0; e < 4; ++e) {
          float xg = __shfl(acc[e], gsrc + 0);
          float xi = __shfl(acc[e], gsrc + 4);
          float xf = __shfl(acc[e], gsrc + 8);
          float xo = __shfl(acc[e], gsrc + 12);
          float cn = cv[e] * fsigm(xf) + ftanh(xg) * fsigm(xi);
          cv[e] = cn;
          float hv = ftanh(cn) * fsigm(xo);
          if (e == 0) hh0 = hv;
          else if (e == 1) hh1 = hv;
          else if (e == 2) hh2 = hv;
          else hh3 = hv;
        }
        int rr = l15 >> 2;
        float hexp = rr == 0 ? hh0 : rr == 1 ? hh1 : rr == 2 ? hh2 : hh3;
        float p0 = __shfl(hexp, psrc + 0);
        float p1s = __shfl(hexp, psrc + 1);
        float p2s = __shfl(hexp, psrc + 2);
        float p3s = __shfl(hexp, psrc + 3);
        if (lane < 16) {
          u64 pk = (u64)(unsigned short)f2bf(p0) | ((u64)(unsigned short)f2bf(p1s) << 16) |
                   ((u64)(unsigned short)f2bf(p2s) << 32) |
                   ((u64)(unsigned short)f2bf(p3s) << 48);
          int idx = (group * 16 + lane) * 256 + nsl * 4 + wv;
          if (r < 256)
            __hip_atomic_store(h2ex + (r & 1) * 16384 + idx, pk, __ATOMIC_RELAXED,
                               __HIP_MEMORY_SCOPE_AGENT);
          else
            hTy[idx] = pk;  // h2(255) = hT_y
        }
      }
    }

    if (r < 256) {
      asm volatile("s_waitcnt vmcnt(0)" ::: "memory");
      __syncthreads();
      if (tid == 0)
        __hip_atomic_store(arr + ((group << 6) + nsl) * 32, (unsigned)(r + 1),
                           __ATOMIC_RELAXED, __HIP_MEMORY_SCOPE_AGENT);
    }
    gcur = gnext;
  }
}

// ---- final projection, split-K=2 --------------------------------------------
__global__ __launch_bounds__(256) void k_final(const short* __restrict__ hT,
                                               const float* __restrict__ W3,
                                               float* __restrict__ partial) {
  __shared__ float hst[64][64];
  int tid = threadIdx.x;
  int n = blockIdx.x * 256 + tid;
  int kbase = blockIdx.y * 512;
  float acc[64];
#pragma unroll
  for (int i = 0; i < 64; ++i) acc[i] = 0.f;
  int bb = tid >> 2, part = tid & 3;
  for (int kc = 0; kc < 512; kc += 64) {
    __syncthreads();
    s16x8 v0 = *(const s16x8*)(hT + bb * HID + kbase + kc + part * 16);
    s16x8 v1 = *(const s16x8*)(hT + bb * HID + kbase + kc + part * 16 + 8);
#pragma unroll
    for (int e = 0; e < 8; ++e) {
      hst[part * 16 + e][bb] = bf2f(v0[e]);
      hst[part * 16 + 8 + e][bb] = bf2f(v1[e]);
    }
    __syncthreads();
    for (int k = 0; k < 64; ++k) {
      float wv = W3[(size_t)(kbase + kc + k) * N_CLASS + n];
      const float4* hp = (const float4*)&hst[k][0];
#pragma unroll
      for (int b4 = 0; b4 < 16; ++b4) {
        float4 h4 = hp[b4];
        acc[b4 * 4 + 0] += h4.x * wv;
        acc[b4 * 4 + 1] += h4.y * wv;
        acc[b4 * 4 + 2] += h4.z * wv;
        acc[b4 * 4 + 3] += h4.w * wv;
      }
    }
  }
#pragma unroll
  for (int b = 0; b < 64; ++b)
    partial[((size_t)blockIdx.y * 64 + b) * N_CLASS + n] = acc[b];
}

__global__ void k_fincomb(const float* __restrict__ partial, const float* __restrict__ b2,
                          float* __restrict__ out) {
  int n = blockIdx.x * 256 + threadIdx.x;
  int b = blockIdx.y;
  out[(size_t)b * N_CLASS + n] =
      partial[(size_t)b * N_CLASS + n] + partial[((size_t)64 + b) * N_CLASS + n] + b2[n];
}

extern "C" void kernel_launch(void* const* d_in, const int* in_sizes, int n_in, void* d_out,
                              int out_size, void* d_ws, size_t ws_size, hipStream_t stream) {
  (void)in_sizes; (void)n_in; (void)out_size; (void)ws_size;
  const int* X = (const int*)d_in[0];
  const float* C = (const float*)d_in[1];
  const float* W1 = (const float*)d_in[2];
  const float* W_xi = (const float*)d_in[3];
  const float* W_xf = (const float*)d_in[4];
  const float* W_xo = (const float*)d_in[5];
  const float* W2 = (const float*)d_in[6];
  const float* W_hi = (const float*)d_in[7];
  const float* W_hf = (const float*)d_in[8];
  const float* W_ho = (const float*)d_in[9];
  const float* b1 = (const float*)d_in[10];
  const float* b_i = (const float*)d_in[11];
  const float* b_f = (const float*)d_in[12];
  const float* b_o = (const float*)d_in[13];
  const float* W1_y = (const float*)d_in[14];
  const float* W_xi_y = (const float*)d_in[15];
  const float* W_xf_y = (const float*)d_in[16];
  const float* W_xo_y = (const float*)d_in[17];
  const float* W2_y = (const float*)d_in[18];
  const float* W_hi_y = (const float*)d_in[19];
  const float* W_hf_y = (const float*)d_in[20];
  const float* W_ho_y = (const float*)d_in[21];
  const float* b1_y = (const float*)d_in[22];
  const float* b_i_y = (const float*)d_in[23];
  const float* b_f_y = (const float*)d_in[24];
  const float* b_o_y = (const float*)d_in[25];
  const float* W3 = (const float*)d_in[26];
  const float* b2 = (const float*)d_in[27];
  const float* h0 = (const float*)d_in[28];
  const float* c0 = (const float*)d_in[29];
  const float* h0_y = (const float*)d_in[30];
  const float* c0_y = (const float*)d_in[31];

  char* w = (char*)d_ws;
  size_t off = 0;
  auto take = [&](size_t bytes) {
    char* p = w + off;
    off += (bytes + 255) & ~(size_t)255;
    return p;
  };
  short* wx1 = (short*)take(64UL * NG4 * 8 * 2);
  short* wh1 = (short*)take(128UL * NG4 * 8 * 2);
  short* wx2 = (short*)take(128UL * NG4 * 8 * 2);
  short* wh2 = (short*)take(128UL * NG4 * 8 * 2);
  short* xs = (short*)take((size_t)SEQ * BATCH * EMB * 2);
  u64* G1sw = (u64*)take((size_t)SEQ * 65536 * 8);  // 134MB; partials alias later
  float* bc1 = (float*)take(NG4 * 4);
  float* bc2 = (float*)take(NG4 * 4);
  u64* h1ex = (u64*)take(2UL * 16384 * 8);
  u64* h2ex = (u64*)take(2UL * 16384 * 8);
  u64* hTy = (u64*)take(16384UL * 8);
  unsigned* flags = (unsigned*)take(65536);

  hipMemsetAsync(flags, 0, 65536, stream);
  k_bcat<<<16, 256, 0, stream>>>(b1, b_i, b_f, b_o, bc1);
  k_bcat<<<16, 256, 0, stream>>>(b1_y, b_i_y, b_f_y, b_o_y, bc2);
  k_f2bf<<<256, 256, 0, stream>>>(h0, (short*)h1ex + 65536, BATCH * HID);
  k_f2bf<<<256, 256, 0, stream>>>(h0_y, (short*)h2ex, BATCH * HID);
  k_conv_w4<<<dim3(256, 1, 4), 256, 0, stream>>>(W1, W_xi, W_xf, W_xo, wx1, 512);
  k_conv_w4<<<dim3(512, 1, 4), 256, 0, stream>>>(W2, W_hi, W_hf, W_ho, wh1, 1024);
  k_conv_w4<<<dim3(512, 1, 4), 256, 0, stream>>>(W1_y, W_xi_y, W_xf_y, W_xo_y, wx2, 1024);
  k_conv_w4<<<dim3(512, 1, 4), 256, 0, stream>>>(W2_y, W_hi_y, W_hf_y, W_ho_y, wh2, 1024);
  k_embed<<<SEQ * BATCH, 256, 0, stream>>>(X, C, xs);
  k_gemx<<<dim3(64, 16), 256, 0, stream>>>(xs, wx1, bc1, G1sw);
  k_mega<<<256, 512, 0, stream>>>(G1sw, wh1, wx2, wh2, bc2, h1ex, h2ex, c0, c0_y, hTy,
                                  flags);
  float* partial = (float*)G1sw;
  k_final<<<dim3(125, 2), 256, 0, stream>>>((const short*)hTy, W3, partial);
  k_fincomb<<<dim3(125, 64), 256, 0, stream>>>(partial, b2, (float*)d_out);
}